// Round 9
// baseline (239.067 us; speedup 1.0000x reference)
//
#include <hip/hip_runtime.h>

#define HN 8
#define NN 4096
#define CC 384
#define DD 48
#define DP 64
#define NPAIR 1225   // (i<=j) over 49 channels
#define PPAD 1280
#define MPF 52       // f-padded row length of pair-major M

typedef unsigned short ushort;
typedef unsigned int uint;
typedef __attribute__((ext_vector_type(8))) short short8;
typedef __attribute__((ext_vector_type(4))) float f32x4;

__device__ __forceinline__ float4 ld4(const float* p){ return *reinterpret_cast<const float4*>(p); }
__device__ __forceinline__ void st4(float* p, const float4& v){ *reinterpret_cast<float4*>(p) = v; }

// RTN float->bf16 bits (inputs finite)
__device__ __forceinline__ uint bf16rtn(float x){
  uint u = __float_as_uint(x);
  return (u + 0x7FFFu + ((u >> 16) & 1u)) >> 16;
}

// ---------------- split fp32 -> bf16 hi/lo planes ----------------
__global__ __launch_bounds__(256) void split_f32(const float* __restrict__ in,
                                                 ushort* __restrict__ hi,
                                                 ushort* __restrict__ lo,
                                                 int n4) {
  int idx = blockIdx.x * 256 + threadIdx.x;
  if (idx >= n4) return;
  float4 v = ld4(in + (size_t)idx * 4);
  float bv[4] = {v.x, v.y, v.z, v.w};
  uint hu[2], lu[2];
#pragma unroll
  for (int e = 0; e < 2; ++e) {
    float x0 = bv[2*e], x1 = bv[2*e+1];
    uint h0 = bf16rtn(x0), h1 = bf16rtn(x1);
    float d0 = x0 - __uint_as_float(h0 << 16);
    float d1 = x1 - __uint_as_float(h1 << 16);
    hu[e] = h0 | (h1 << 16);
    lu[e] = (__float_as_uint(d0) >> 16) | (__float_as_uint(d1) & 0xFFFF0000u);
  }
  *reinterpret_cast<uint2*>(hi + (size_t)idx*4) = make_uint2(hu[0], hu[1]);
  *reinterpret_cast<uint2*>(lo + (size_t)idx*4) = make_uint2(lu[0], lu[1]);
}

// ---------------- MFMA NT GEMM (split bf16 A pre-split; B split on the fly) ----
// C[m][n] = sum_k A[m][k]*B[n][k] + bias[n]
#define GST 40   // ushort row stride in LDS (80 B): kvmod-proven bank spread
__global__ __launch_bounds__(256) void gemm_bf16(const ushort* __restrict__ Ah,
                                                 const ushort* __restrict__ Al,
                                                 const float*  __restrict__ Bw,
                                                 const float*  __restrict__ bias,
                                                 float* __restrict__ Cm,
                                                 int M, int Nc, int K) {
  __shared__ ushort AsH[2][128*GST], AsL[2][128*GST];
  __shared__ ushort BsH[2][64*GST],  BsL[2][64*GST];
  const int tid = threadIdx.x;
  const int n0 = blockIdx.x * 64;    // col-tile fastest: consecutive WGs share A panel
  const int m0 = blockIdx.y * 128;
  const int lane = tid & 63, wv = tid >> 6;
  const int wr = wv >> 1, wc = wv & 1;
  const int lr = lane & 15, lg = lane >> 4;
  const int ar = tid >> 1, ap = (tid & 1) << 4;   // A stage: row, 16-k half
  const int br = tid >> 2, bp = (tid & 3) << 3;   // B stage: row, 8-k quarter
  const ushort* gAh = Ah + (size_t)(m0 + ar) * K + ap;
  const ushort* gAl = Al + (size_t)(m0 + ar) * K + ap;
  const float*  gB  = Bw + (size_t)(n0 + br) * K + bp;
  uint4 rah0, rah1, ral0, ral1;
  float4 rb0, rb1;
#define G_LOAD(T) { int kk = (T)*32; \
    rah0 = *reinterpret_cast<const uint4*>(gAh + kk); \
    rah1 = *reinterpret_cast<const uint4*>(gAh + kk + 8); \
    ral0 = *reinterpret_cast<const uint4*>(gAl + kk); \
    ral1 = *reinterpret_cast<const uint4*>(gAl + kk + 8); \
    rb0 = ld4(gB + kk); rb1 = ld4(gB + kk + 4); }
#define G_WRITE(BUF) { \
    *reinterpret_cast<uint4*>(&AsH[BUF][ar*GST+ap])   = rah0; \
    *reinterpret_cast<uint4*>(&AsH[BUF][ar*GST+ap+8]) = rah1; \
    *reinterpret_cast<uint4*>(&AsL[BUF][ar*GST+ap])   = ral0; \
    *reinterpret_cast<uint4*>(&AsL[BUF][ar*GST+ap+8]) = ral1; \
    float bv[8] = {rb0.x,rb0.y,rb0.z,rb0.w,rb1.x,rb1.y,rb1.z,rb1.w}; \
    uint hu[4], lu[4]; \
    _Pragma("unroll") for (int e = 0; e < 4; ++e) { \
      float x0 = bv[2*e], x1 = bv[2*e+1]; \
      uint h0 = bf16rtn(x0), h1 = bf16rtn(x1); \
      float d0 = x0 - __uint_as_float(h0 << 16); \
      float d1 = x1 - __uint_as_float(h1 << 16); \
      hu[e] = h0 | (h1 << 16); \
      lu[e] = (__float_as_uint(d0) >> 16) | (__float_as_uint(d1) & 0xFFFF0000u); } \
    *reinterpret_cast<uint4*>(&BsH[BUF][br*GST+bp]) = make_uint4(hu[0],hu[1],hu[2],hu[3]); \
    *reinterpret_cast<uint4*>(&BsL[BUF][br*GST+bp]) = make_uint4(lu[0],lu[1],lu[2],lu[3]); }

  f32x4 acc[4][2];
#pragma unroll
  for (int pf = 0; pf < 4; ++pf)
#pragma unroll
    for (int ff = 0; ff < 2; ++ff) acc[pf][ff] = (f32x4)0.f;

  G_LOAD(0);
  G_WRITE(0);
  G_LOAD(1);
  const int NT = K / 32;
  int cur = 0;
  __syncthreads();
  for (int t = 0; t < NT; ++t) {
    short8 a_h[4], a_l[4], b_h[2], b_l[2];
#pragma unroll
    for (int pf = 0; pf < 4; ++pf) {
      int row = wr*64 + pf*16 + lr;
      a_h[pf] = *reinterpret_cast<const short8*>(&AsH[cur][row*GST + lg*8]);
      a_l[pf] = *reinterpret_cast<const short8*>(&AsL[cur][row*GST + lg*8]);
    }
#pragma unroll
    for (int ff = 0; ff < 2; ++ff) {
      int col = wc*32 + ff*16 + lr;
      b_h[ff] = *reinterpret_cast<const short8*>(&BsH[cur][col*GST + lg*8]);
      b_l[ff] = *reinterpret_cast<const short8*>(&BsL[cur][col*GST + lg*8]);
    }
    if (t < NT-1) { G_WRITE(cur^1); }
    if (t < NT-2) { G_LOAD(t+2); }
#pragma unroll
    for (int pf = 0; pf < 4; ++pf)
#pragma unroll
      for (int ff = 0; ff < 2; ++ff) {
        acc[pf][ff] = __builtin_amdgcn_mfma_f32_16x16x32_bf16(a_h[pf], b_h[ff], acc[pf][ff], 0, 0, 0);
        acc[pf][ff] = __builtin_amdgcn_mfma_f32_16x16x32_bf16(a_h[pf], b_l[ff], acc[pf][ff], 0, 0, 0);
        acc[pf][ff] = __builtin_amdgcn_mfma_f32_16x16x32_bf16(a_l[pf], b_h[ff], acc[pf][ff], 0, 0, 0);
      }
    __syncthreads();
    cur ^= 1;
  }
  // epilogue: row = m0+wr*64+pf*16+lg*4+reg, col = n0+wc*32+ff*16+lr
#pragma unroll
  for (int pf = 0; pf < 4; ++pf)
#pragma unroll
    for (int ff = 0; ff < 2; ++ff) {
      int col = n0 + wc*32 + ff*16 + lr;
      float bs = bias[col];
#pragma unroll
      for (int reg = 0; reg < 4; ++reg) {
        int row = m0 + wr*64 + pf*16 + lg*4 + reg;
        Cm[(size_t)row*Nc + col] = acc[pf][ff][reg] + bs;
      }
    }
#undef G_LOAD
#undef G_WRITE
}

// ---------------- prep: norms + layouts ----------------
__global__ __launch_bounds__(256) void prep2(const float* __restrict__ qkv,
                                             const float* __restrict__ temperature,
                                             float* __restrict__ Qb,
                                             float* __restrict__ KbT,
                                             ushort* __restrict__ VhT,
                                             ushort* __restrict__ VlT) {
  __shared__ float Ks[64*65];
  __shared__ float Vs[64*65];
  const int nb = blockIdx.x;        // 0..63
  const int h  = blockIdx.y;
  const int lane = threadIdx.x & 63;
  const int w = threadIdx.x >> 6;
  const float temp = temperature[h];
  const float CINV = 0.05103103630798288f;   // 384^-0.5
  const float S4   = 2.6321480259049848f;    // 48^0.25
  for (int r = 0; r < 16; ++r) {
    const int nl = w*16 + r;
    const int n  = nb*64 + nl;
    const float* row = qkv + (size_t)n * (3*CC) + h * DD;
    float qv = (lane < DD) ? row[lane] : 0.f;
    float kv = (lane < DD) ? row[CC + lane] : 0.f;
    float vv = (lane >= 1 && lane <= DD) ? row[2*CC + lane - 1] : 0.f;
    float qs = qv * CINV;
    float q2 = qs * qs;
    float k2 = kv * kv;
#pragma unroll
    for (int off = 32; off > 0; off >>= 1) {
      q2 += __shfl_xor(q2, off);
      k2 += __shfl_xor(k2, off);
    }
    float qn = qs / fmaxf(sqrtf(q2), 1e-12f) * (S4 * temp);
    float kn = kv / fmaxf(sqrtf(k2), 1e-12f) * S4;
    float qo = (lane < DD) ? qn : ((lane == DD) ? 6.928203230275509f : 0.f);
    float ko = (lane < DD) ? kn : ((lane == DD) ? 1.f : 0.f);
    float vo = (lane == 0) ? (1.f/NN) : ((lane <= DD) ? vv * (1.f/NN) : 0.f);
    Qb[((size_t)h * NN + n) * DP + lane] = qo;
    Ks[nl*65 + lane] = ko;
    Vs[nl*65 + lane] = vo;
  }
  __syncthreads();
  const int ch = threadIdx.x >> 2;
  const int q4 = threadIdx.x & 3;
  float kc[16], vc[16];
#pragma unroll
  for (int e = 0; e < 16; ++e) {
    int nl = q4*16 + e;
    kc[e] = Ks[nl*65 + ch];
    vc[e] = Vs[nl*65 + ch];
  }
  size_t tbase = ((size_t)h*64 + ch) * NN + nb*64 + q4*16;
#pragma unroll
  for (int e = 0; e < 16; e += 4)
    st4(KbT + tbase + e, make_float4(kc[e], kc[e+1], kc[e+2], kc[e+3]));
  uint hu[8], lu[8];
#pragma unroll
  for (int e = 0; e < 8; ++e) {
    float v0 = vc[2*e], v1 = vc[2*e+1];
    uint h0 = bf16rtn(v0), h1 = bf16rtn(v1);
    float d0 = v0 - __uint_as_float(h0 << 16);
    float d1 = v1 - __uint_as_float(h1 << 16);
    uint t0 = __float_as_uint(d0), t1 = __float_as_uint(d1);
    hu[e] = h0 | (h1 << 16);
    lu[e] = (t0 >> 16) | (t1 & 0xFFFF0000u);
  }
  *reinterpret_cast<uint4*>(VhT + tbase)     = make_uint4(hu[0],hu[1],hu[2],hu[3]);
  *reinterpret_cast<uint4*>(VhT + tbase + 8) = make_uint4(hu[4],hu[5],hu[6],hu[7]);
  *reinterpret_cast<uint4*>(VlT + tbase)     = make_uint4(lu[0],lu[1],lu[2],lu[3]);
  *reinterpret_cast<uint4*>(VlT + tbase + 8) = make_uint4(lu[4],lu[5],lu[6],lu[7]);
}

// ---------------- kvmod via MFMA (split bf16) ----------------
#define KST 40
#define KNST 36
__global__ __launch_bounds__(256) void kvmod_mfma(const float* __restrict__ KbT,
                                                  const ushort* __restrict__ VhT,
                                                  const ushort* __restrict__ VlT,
                                                  float* __restrict__ Mp) {
  __shared__ ushort KKh[256*KST];
  __shared__ ushort KKl[256*KST];
  __shared__ float  KnS[64*KNST];
  __shared__ ushort VhS[64*KST];
  __shared__ ushort VlS[64*KST];
  const int tid  = threadIdx.x;
  const int p0   = blockIdx.x * 256;
  const int h    = blockIdx.y;
  const int part = blockIdx.z;
  const int nbase = part * 512;
  int ii = 63, jj = 63;
  {
    int pg = p0 + tid;
    if (pg < NPAIR) {
      int i = 0, rem = pg;
      while (rem >= 49 - i) { rem -= 49 - i; ++i; }
      ii = i; jj = i + rem;
    }
  }
  const float* krow_i = &KnS[ii*KNST];
  const float* krow_j = &KnS[jj*KNST];
  const int sch = tid >> 2;
  const int sq  = tid & 3;
  const size_t kgbase = ((size_t)h*64 + sch) * NN + nbase;
  const int lane = tid & 63, wv = tid >> 6;
  const int lr = lane & 15, lg = lane >> 4;
  f32x4 acc[4][4];
#pragma unroll
  for (int a = 0; a < 4; ++a)
#pragma unroll
    for (int b = 0; b < 4; ++b) acc[a][b] = (f32x4)0.f;

  for (int t = 0; t < 16; ++t) {
    const int k0 = t * 32;
    __syncthreads();
    {
      float4 a0 = ld4(KbT + kgbase + k0 + sq*8);
      float4 a1 = ld4(KbT + kgbase + k0 + sq*8 + 4);
      st4(&KnS[sch*KNST + sq*8], a0);
      st4(&KnS[sch*KNST + sq*8 + 4], a1);
      *reinterpret_cast<uint4*>(&VhS[sch*KST + sq*8]) =
          *reinterpret_cast<const uint4*>(VhT + kgbase + k0 + sq*8);
      *reinterpret_cast<uint4*>(&VlS[sch*KST + sq*8]) =
          *reinterpret_cast<const uint4*>(VlT + kgbase + k0 + sq*8);
    }
    __syncthreads();
    {
      uint hu[16], lu[16];
#pragma unroll
      for (int g = 0; g < 8; ++g) {
        float4 a = ld4(krow_i + g*4);
        float4 b = ld4(krow_j + g*4);
        float m0 = a.x*b.x, m1 = a.y*b.y, m2 = a.z*b.z, m3 = a.w*b.w;
        uint h0 = bf16rtn(m0), h1 = bf16rtn(m1), h2 = bf16rtn(m2), h3 = bf16rtn(m3);
        float d0 = m0 - __uint_as_float(h0 << 16);
        float d1 = m1 - __uint_as_float(h1 << 16);
        float d2 = m2 - __uint_as_float(h2 << 16);
        float d3 = m3 - __uint_as_float(h3 << 16);
        uint t0 = __float_as_uint(d0), t1 = __float_as_uint(d1);
        uint t2 = __float_as_uint(d2), t3 = __float_as_uint(d3);
        hu[2*g]   = h0 | (h1 << 16);
        hu[2*g+1] = h2 | (h3 << 16);
        lu[2*g]   = (t0 >> 16) | (t1 & 0xFFFF0000u);
        lu[2*g+1] = (t2 >> 16) | (t3 & 0xFFFF0000u);
      }
      uint4* dh = reinterpret_cast<uint4*>(&KKh[tid*KST]);
      uint4* dl = reinterpret_cast<uint4*>(&KKl[tid*KST]);
      dh[0] = make_uint4(hu[0],hu[1],hu[2],hu[3]);
      dh[1] = make_uint4(hu[4],hu[5],hu[6],hu[7]);
      dh[2] = make_uint4(hu[8],hu[9],hu[10],hu[11]);
      dh[3] = make_uint4(hu[12],hu[13],hu[14],hu[15]);
      dl[0] = make_uint4(lu[0],lu[1],lu[2],lu[3]);
      dl[1] = make_uint4(lu[4],lu[5],lu[6],lu[7]);
      dl[2] = make_uint4(lu[8],lu[9],lu[10],lu[11]);
      dl[3] = make_uint4(lu[12],lu[13],lu[14],lu[15]);
    }
    __syncthreads();
    short8 ah[4], al[4], bh[4], bl[4];
#pragma unroll
    for (int pf = 0; pf < 4; ++pf) {
      int prow = wv*64 + pf*16 + lr;
      ah[pf] = *reinterpret_cast<const short8*>(&KKh[prow*KST + lg*8]);
      al[pf] = *reinterpret_cast<const short8*>(&KKl[prow*KST + lg*8]);
    }
#pragma unroll
    for (int ff = 0; ff < 4; ++ff) {
      int frow = ff*16 + lr;
      bh[ff] = *reinterpret_cast<const short8*>(&VhS[frow*KST + lg*8]);
      bl[ff] = *reinterpret_cast<const short8*>(&VlS[frow*KST + lg*8]);
    }
#pragma unroll
    for (int pf = 0; pf < 4; ++pf)
#pragma unroll
      for (int ff = 0; ff < 4; ++ff) {
        acc[pf][ff] = __builtin_amdgcn_mfma_f32_16x16x32_bf16(ah[pf], bh[ff], acc[pf][ff], 0, 0, 0);
        acc[pf][ff] = __builtin_amdgcn_mfma_f32_16x16x32_bf16(ah[pf], bl[ff], acc[pf][ff], 0, 0, 0);
        acc[pf][ff] = __builtin_amdgcn_mfma_f32_16x16x32_bf16(al[pf], bh[ff], acc[pf][ff], 0, 0, 0);
      }
  }
  float* out = Mp + ((size_t)(part*HN + h) * PPAD + p0 + wv*64) * MPF;
#pragma unroll
  for (int pf = 0; pf < 4; ++pf)
#pragma unroll
    for (int ff = 0; ff < 4; ++ff) {
      int f = ff*16 + lr;
      if (f < MPF) {
#pragma unroll
        for (int reg = 0; reg < 4; ++reg) {
          int prow = pf*16 + lg*4 + reg;
          out[prow*MPF + f] = acc[pf][ff][reg];
        }
      }
    }
}

// ---------------- reduce parts + mirror into f-major bf16 slices ----------------
__global__ __launch_bounds__(256) void reduce_mirror(const float* __restrict__ Mp,
                                                     ushort* __restrict__ Mbh,
                                                     ushort* __restrict__ Mbl,
                                                     float* __restrict__ Mnorm) {
  const int pb = blockIdx.x;      // 0..19
  const int h  = blockIdx.y;
  const int pl = threadIdx.x & 63;
  const int fq0 = threadIdx.x >> 6;   // 0..3
  const int p = pb*64 + pl;
  if (p >= NPAIR) return;
  int i = 0, rem = p;
  while (rem >= 49 - i) { rem -= 49 - i; ++i; }
  const int j = i + rem;
  for (int fq = fq0; fq < 13; fq += 4) {
    float4 s = make_float4(0.f, 0.f, 0.f, 0.f);
#pragma unroll
    for (int part = 0; part < 8; ++part) {
      float4 a = ld4(Mp + ((size_t)(part*HN + h) * PPAD + p) * MPF + fq*4);
      s.x += a.x; s.y += a.y; s.z += a.z; s.w += a.w;
    }
    float sv[4] = {s.x, s.y, s.z, s.w};
#pragma unroll
    for (int c = 0; c < 4; ++c) {
      int f = fq*4 + c;
      float v = sv[c];
      uint hb = bf16rtn(v);
      float d = v - __uint_as_float(hb << 16);
      ushort lb = (ushort)(__float_as_uint(d) >> 16);
      size_t a1 = (((size_t)h*49 + i)*64 + f)*64 + j;
      size_t a2 = (((size_t)h*49 + j)*64 + f)*64 + i;
      Mbh[a1] = (ushort)hb; Mbl[a1] = lb;
      Mbh[a2] = (ushort)hb; Mbl[a2] = lb;
    }
    if (p == NPAIR-1) st4(&Mnorm[h*64 + fq*4], s);   // pair (48,48)
  }
}

// ---------------- y via MFMA, v5: barrier-free loop, frags direct from L1/L2 ----
// B-frags are identical across the WG's 4 waves and across all 32 n-blocks of an
// (h,zi,zf) -> L1/L2 serve them. No LDS staging of M => NO __syncthreads in the
// i-loop => no vmcnt(0) barrier drain; ping-pong register prefetch (static names).
__global__ __launch_bounds__(256, 3) void y_mfma(const float* __restrict__ Qb,
                                                 const ushort* __restrict__ Mbh,
                                                 const ushort* __restrict__ Mbl,
                                                 float* __restrict__ Yp) {
  __shared__ float QT[28*128];
  const int tid = threadIdx.x;
  const int h = blockIdx.y;
  const int n0 = blockIdx.x * 128;
  const int zi = blockIdx.z >> 1;
  const int zf = blockIdx.z & 1;
  const int ibase = zi * 25;
  const int ni = zi ? 24 : 25;
  const int lane = tid & 63;
  const int wv = tid >> 6;
  const int lr = lane & 15, lg = lane >> 4;

  // ---- stage QT: channels [ibase, ibase+ni) transposed for 128 rows ----
  {
    const int ng = (ni + 3) >> 2;
    for (int v = tid; v < ng*128; v += 256) {
      int r = v & 127;
      int cg = v >> 7;
      float4 q = ld4(Qb + ((size_t)h*NN + n0 + r)*DP + ibase + cg*4);
      QT[(cg*4+0)*128 + r] = q.x;
      QT[(cg*4+1)*128 + r] = q.y;
      QT[(cg*4+2)*128 + r] = q.z;
      QT[(cg*4+3)*128 + r] = q.w;
    }
  }
  // ---- A-frags (constant): row = n0+wv*32+m*16+lr, k = kc*32+lg*8+e ----
  short8 ah[2][2], al[2][2];
#pragma unroll
  for (int m = 0; m < 2; ++m) {
    const float* qr = Qb + ((size_t)h*NN + n0 + wv*32 + m*16 + lr)*DP + lg*8;
#pragma unroll
    for (int kc = 0; kc < 2; ++kc) {
      float4 v0 = ld4(qr + kc*32);
      float4 v1 = ld4(qr + kc*32 + 4);
      float qv[8] = {v0.x,v0.y,v0.z,v0.w,v1.x,v1.y,v1.z,v1.w};
      union { uint u[4]; short8 s; } chh, cll;
#pragma unroll
      for (int e = 0; e < 4; ++e) {
        float x0 = qv[2*e], x1 = qv[2*e+1];
        uint h0 = bf16rtn(x0), h1 = bf16rtn(x1);
        float d0 = x0 - __uint_as_float(h0 << 16);
        float d1 = x1 - __uint_as_float(h1 << 16);
        chh.u[e] = h0 | (h1 << 16);
        cll.u[e] = (__float_as_uint(d0) >> 16) | (__float_as_uint(d1) & 0xFFFF0000u);
      }
      ah[m][kc] = chh.s;
      al[m][kc] = cll.s;
    }
  }
  // ---- fragment source pointers (wave-identical within WG -> L1 hits) ----
  // frag(kc,ff) at slice i: gH/gL + i*4096 + ff*1024 + kc*32 + lr*64 + lg*8
  const ushort* gH = Mbh + (((size_t)h*49 + ibase)*64 + zf*32)*64 + lr*64 + lg*8;
  const ushort* gL = Mbl + (((size_t)h*49 + ibase)*64 + zf*32)*64 + lr*64 + lg*8;
#define RC(p) (*reinterpret_cast<const short8*>(p))
#define LOADF(BH, BL, LI) { size_t sb = (size_t)(LI)*4096; \
    BH[0][0] = RC(gH + sb);               BH[0][1] = RC(gH + sb + 1024); \
    BH[1][0] = RC(gH + sb + 32);          BH[1][1] = RC(gH + sb + 1024 + 32); \
    BL[0][0] = RC(gL + sb);               BL[0][1] = RC(gL + sb + 1024); \
    BL[1][0] = RC(gL + sb + 32);          BL[1][1] = RC(gL + sb + 1024 + 32); }
#define COMPUTE(BH, BL, LI) { \
    _Pragma("unroll") for (int m = 0; m < 2; ++m) { \
      float4 qi = ld4(&QT[(LI)*128 + wv*32 + m*16 + lg*4]); \
      _Pragma("unroll") for (int ff = 0; ff < 2; ++ff) { \
        f32x4 acc = (f32x4)0.f; \
        acc = __builtin_amdgcn_mfma_f32_16x16x32_bf16(ah[m][0], BH[0][ff], acc, 0, 0, 0); \
        acc = __builtin_amdgcn_mfma_f32_16x16x32_bf16(ah[m][0], BL[0][ff], acc, 0, 0, 0); \
        acc = __builtin_amdgcn_mfma_f32_16x16x32_bf16(al[m][0], BH[0][ff], acc, 0, 0, 0); \
        acc = __builtin_amdgcn_mfma_f32_16x16x32_bf16(ah[m][1], BH[1][ff], acc, 0, 0, 0); \
        acc = __builtin_amdgcn_mfma_f32_16x16x32_bf16(ah[m][1], BL[1][ff], acc, 0, 0, 0); \
        acc = __builtin_amdgcn_mfma_f32_16x16x32_bf16(al[m][1], BH[1][ff], acc, 0, 0, 0); \
        ya[m][ff][0] += qi.x * acc[0]; \
        ya[m][ff][1] += qi.y * acc[1]; \
        ya[m][ff][2] += qi.z * acc[2]; \
        ya[m][ff][3] += qi.w * acc[3]; } } }

  f32x4 ya[2][2];
#pragma unroll
  for (int m = 0; m < 2; ++m)
#pragma unroll
    for (int ff = 0; ff < 2; ++ff) ya[m][ff] = (f32x4)0.f;

  short8 pAh[2][2], pAl[2][2];   // ping
  short8 pBh[2][2], pBl[2][2];   // pong
  LOADF(pAh, pAl, 0);
  __syncthreads();               // QT ready (the only barrier)
  int li = 0;
  while (li + 1 < ni) {
    LOADF(pBh, pBl, li+1);
    COMPUTE(pAh, pAl, li);
    if (li + 2 < ni) { LOADF(pAh, pAl, li+2); }
    COMPUTE(pBh, pBl, li+1);
    li += 2;
  }
  if (li < ni) { COMPUTE(pAh, pAl, li); }

  // ---- write raw partials (disjoint f across zf; summed over zi by combine) ----
  float* out = Yp + ((size_t)(zi*HN + h) * NN) * 64;
#pragma unroll
  for (int m = 0; m < 2; ++m)
#pragma unroll
    for (int ff = 0; ff < 2; ++ff) {
      int f = zf*32 + ff*16 + lr;
#pragma unroll
      for (int reg = 0; reg < 4; ++reg) {
        int row = n0 + wv*32 + m*16 + lg*4 + reg;
        out[(size_t)row*64 + f] = ya[m][ff][reg];
      }
    }
#undef RC
#undef LOADF
#undef COMPUTE
}

// ---------------- combine partials -> split-bf16 attn planes ----------------
__global__ __launch_bounds__(256) void y_combine(const float* __restrict__ Yp,
                                                 const float* __restrict__ Mnorm,
                                                 ushort* __restrict__ AttnH,
                                                 ushort* __restrict__ AttnL) {
  const int h = blockIdx.y;
  const int t = threadIdx.x;
  const int r = blockIdx.x*64 + (t >> 2);
  const int fq = t & 3;
  const int lane = t & 63;
  const float* p0 = Yp + ((size_t)h*NN + r)*64 + fq*16;
  const float* p1 = Yp + ((size_t)(HN+h)*NN + r)*64 + fq*16;
  float y[16];
#pragma unroll
  for (int g = 0; g < 4; ++g) {
    float4 a = ld4(p0 + g*4);
    float4 b = ld4(p1 + g*4);
    float4 m = ld4(Mnorm + h*64 + fq*16 + g*4);
    y[g*4+0] = 0.5f*(a.x+b.x) + 24.f*m.x;
    y[g*4+1] = 0.5f*(a.y+b.y) + 24.f*m.y;
    y[g*4+2] = 0.5f*(a.z+b.z) + 24.f*m.z;
    y[g*4+3] = 0.5f*(a.w+b.w) + 24.f*m.w;
  }
  float y0 = __shfl(y[0], lane & ~3);
  float inv = 1.f / y0;
#pragma unroll
  for (int e = 0; e < 16; ++e) {
    int f = fq*16 + e;
    if (f >= 1 && f <= DD) {
      float o = y[e] * inv;
      uint hb = bf16rtn(o);
      float d = o - __uint_as_float(hb << 16);
      size_t a = (size_t)r*CC + h*DD + (f-1);
      AttnH[a] = (ushort)hb;
      AttnL[a] = (ushort)(__float_as_uint(d) >> 16);
    }
  }
}

extern "C" void kernel_launch(void* const* d_in, const int* in_sizes, int n_in,
                              void* d_out, int out_size, void* d_ws, size_t ws_size,
                              hipStream_t stream) {
  const float* x      = (const float*)d_in[0];
  const float* qkv_w  = (const float*)d_in[1];
  const float* qkv_b  = (const float*)d_in[2];
  const float* proj_w = (const float*)d_in[3];
  const float* proj_b = (const float*)d_in[4];
  const float* temp   = (const float*)d_in[5];
  float* ws = (float*)d_ws;

  // Region A [0, 4,718,592): qkv -> Mp -> Yp
  float*  qkv  = ws;
  float*  Mp   = ws;
  float*  Yp   = ws;
  // Region B: Qb
  float*  Qb   = ws + 4718592;
  // Region C [6,815,744, 8,912,896): Xh|Xl (split_x->gemm1) -> KbT (prep2->kvmod) -> Mbh|Mbl|Mnorm
  ushort* Xh   = (ushort*)(ws + 6815744);    // 1,572,864 us
  ushort* Xl   = Xh + 1572864;
  float*  KbT  = ws + 6815744;
  ushort* Mbh  = (ushort*)(ws + 6815744);
  ushort* Mbl  = Mbh + 1605632;
  float*  Mnorm= ws + 6815744 + 1605632;
  // Region D [8,912,896, 11,010,048): VhT|VlT (prep2->kvmod) -> AttnH|AttnL (y_combine->gemm2)
  ushort* VhT  = (ushort*)(ws + 8912896);
  ushort* VlT  = (ushort*)(ws + 9961472);
  ushort* AttnH= (ushort*)(ws + 8912896);
  ushort* AttnL= AttnH + 1572864;

  split_f32<<<1536, 256, 0, stream>>>(x, Xh, Xl, NN*CC/4);
  {
    dim3 g(1152/64, 4096/128);
    gemm_bf16<<<g, 256, 0, stream>>>(Xh, Xl, qkv_w, qkv_b, qkv, 4096, 1152, 384);
  }
  {
    dim3 g(64, HN);
    prep2<<<g, 256, 0, stream>>>(qkv, temp, Qb, KbT, VhT, VlT);
  }
  {
    dim3 g(PPAD/256, HN, 8);
    kvmod_mfma<<<g, 256, 0, stream>>>(KbT, VhT, VlT, Mp);
  }
  hipMemsetAsync((void*)Mbh, 0, 2*(size_t)1605632*2 + 2048, stream);
  {
    dim3 g(PPAD/64, HN);
    reduce_mirror<<<g, 256, 0, stream>>>(Mp, Mbh, Mbl, Mnorm);
  }
  {
    dim3 g(4096/128, HN, 4);
    y_mfma<<<g, 256, 0, stream>>>(Qb, Mbh, Mbl, Yp);
  }
  {
    dim3 g(4096/64, HN);
    y_combine<<<g, 256, 0, stream>>>(Yp, Mnorm, AttnH, AttnL);
  }
  {
    dim3 g(384/64, 4096/128);
    gemm_bf16<<<g, 256, 0, stream>>>(AttnH, AttnL, proj_w, proj_b, (float*)d_out, 4096, 384, 384);
  }
}

// Round 10
// 202.964 us; speedup vs baseline: 1.1779x; 1.1779x over previous
//
#include <hip/hip_runtime.h>

#define HN 8
#define NN 4096
#define CC 384
#define DD 48
#define DP 64
#define NPAIR 1225   // (i<=j) over 49 channels
#define PPAD 1280
#define MPF 52       // f-padded row length of pair-major M

typedef unsigned short ushort;
typedef unsigned int uint;
typedef __attribute__((ext_vector_type(8))) short short8;
typedef __attribute__((ext_vector_type(4))) float f32x4;

__device__ __forceinline__ float4 ld4(const float* p){ return *reinterpret_cast<const float4*>(p); }
__device__ __forceinline__ void st4(float* p, const float4& v){ *reinterpret_cast<float4*>(p) = v; }

// RTN float->bf16 bits (inputs finite)
__device__ __forceinline__ uint bf16rtn(float x){
  uint u = __float_as_uint(x);
  return (u + 0x7FFFu + ((u >> 16) & 1u)) >> 16;
}

// ---------------- split fp32 -> bf16 hi/lo planes ----------------
__global__ __launch_bounds__(256) void split_f32(const float* __restrict__ in,
                                                 ushort* __restrict__ hi,
                                                 ushort* __restrict__ lo,
                                                 int n4) {
  int idx = blockIdx.x * 256 + threadIdx.x;
  if (idx >= n4) return;
  float4 v = ld4(in + (size_t)idx * 4);
  float bv[4] = {v.x, v.y, v.z, v.w};
  uint hu[2], lu[2];
#pragma unroll
  for (int e = 0; e < 2; ++e) {
    float x0 = bv[2*e], x1 = bv[2*e+1];
    uint h0 = bf16rtn(x0), h1 = bf16rtn(x1);
    float d0 = x0 - __uint_as_float(h0 << 16);
    float d1 = x1 - __uint_as_float(h1 << 16);
    hu[e] = h0 | (h1 << 16);
    lu[e] = (__float_as_uint(d0) >> 16) | (__float_as_uint(d1) & 0xFFFF0000u);
  }
  *reinterpret_cast<uint2*>(hi + (size_t)idx*4) = make_uint2(hu[0], hu[1]);
  *reinterpret_cast<uint2*>(lo + (size_t)idx*4) = make_uint2(lu[0], lu[1]);
}

// ---------------- MFMA NT GEMM (split bf16 A pre-split; B split on the fly) ----
// C[m][n] = sum_k A[m][k]*B[n][k] + bias[n]
#define GST 40   // ushort row stride in LDS (80 B): kvmod-proven bank spread
__global__ __launch_bounds__(256) void gemm_bf16(const ushort* __restrict__ Ah,
                                                 const ushort* __restrict__ Al,
                                                 const float*  __restrict__ Bw,
                                                 const float*  __restrict__ bias,
                                                 float* __restrict__ Cm,
                                                 int M, int Nc, int K) {
  __shared__ ushort AsH[2][128*GST], AsL[2][128*GST];
  __shared__ ushort BsH[2][64*GST],  BsL[2][64*GST];
  const int tid = threadIdx.x;
  const int n0 = blockIdx.x * 64;    // col-tile fastest: consecutive WGs share A panel
  const int m0 = blockIdx.y * 128;
  const int lane = tid & 63, wv = tid >> 6;
  const int wr = wv >> 1, wc = wv & 1;
  const int lr = lane & 15, lg = lane >> 4;
  const int ar = tid >> 1, ap = (tid & 1) << 4;   // A stage: row, 16-k half
  const int br = tid >> 2, bp = (tid & 3) << 3;   // B stage: row, 8-k quarter
  const ushort* gAh = Ah + (size_t)(m0 + ar) * K + ap;
  const ushort* gAl = Al + (size_t)(m0 + ar) * K + ap;
  const float*  gB  = Bw + (size_t)(n0 + br) * K + bp;
  uint4 rah0, rah1, ral0, ral1;
  float4 rb0, rb1;
#define G_LOAD(T) { int kk = (T)*32; \
    rah0 = *reinterpret_cast<const uint4*>(gAh + kk); \
    rah1 = *reinterpret_cast<const uint4*>(gAh + kk + 8); \
    ral0 = *reinterpret_cast<const uint4*>(gAl + kk); \
    ral1 = *reinterpret_cast<const uint4*>(gAl + kk + 8); \
    rb0 = ld4(gB + kk); rb1 = ld4(gB + kk + 4); }
#define G_WRITE(BUF) { \
    *reinterpret_cast<uint4*>(&AsH[BUF][ar*GST+ap])   = rah0; \
    *reinterpret_cast<uint4*>(&AsH[BUF][ar*GST+ap+8]) = rah1; \
    *reinterpret_cast<uint4*>(&AsL[BUF][ar*GST+ap])   = ral0; \
    *reinterpret_cast<uint4*>(&AsL[BUF][ar*GST+ap+8]) = ral1; \
    float bv[8] = {rb0.x,rb0.y,rb0.z,rb0.w,rb1.x,rb1.y,rb1.z,rb1.w}; \
    uint hu[4], lu[4]; \
    _Pragma("unroll") for (int e = 0; e < 4; ++e) { \
      float x0 = bv[2*e], x1 = bv[2*e+1]; \
      uint h0 = bf16rtn(x0), h1 = bf16rtn(x1); \
      float d0 = x0 - __uint_as_float(h0 << 16); \
      float d1 = x1 - __uint_as_float(h1 << 16); \
      hu[e] = h0 | (h1 << 16); \
      lu[e] = (__float_as_uint(d0) >> 16) | (__float_as_uint(d1) & 0xFFFF0000u); } \
    *reinterpret_cast<uint4*>(&BsH[BUF][br*GST+bp]) = make_uint4(hu[0],hu[1],hu[2],hu[3]); \
    *reinterpret_cast<uint4*>(&BsL[BUF][br*GST+bp]) = make_uint4(lu[0],lu[1],lu[2],lu[3]); }

  f32x4 acc[4][2];
#pragma unroll
  for (int pf = 0; pf < 4; ++pf)
#pragma unroll
    for (int ff = 0; ff < 2; ++ff) acc[pf][ff] = (f32x4)0.f;

  G_LOAD(0);
  G_WRITE(0);
  G_LOAD(1);
  const int NT = K / 32;
  int cur = 0;
  __syncthreads();
  for (int t = 0; t < NT; ++t) {
    short8 a_h[4], a_l[4], b_h[2], b_l[2];
#pragma unroll
    for (int pf = 0; pf < 4; ++pf) {
      int row = wr*64 + pf*16 + lr;
      a_h[pf] = *reinterpret_cast<const short8*>(&AsH[cur][row*GST + lg*8]);
      a_l[pf] = *reinterpret_cast<const short8*>(&AsL[cur][row*GST + lg*8]);
    }
#pragma unroll
    for (int ff = 0; ff < 2; ++ff) {
      int col = wc*32 + ff*16 + lr;
      b_h[ff] = *reinterpret_cast<const short8*>(&BsH[cur][col*GST + lg*8]);
      b_l[ff] = *reinterpret_cast<const short8*>(&BsL[cur][col*GST + lg*8]);
    }
    if (t < NT-1) { G_WRITE(cur^1); }
    if (t < NT-2) { G_LOAD(t+2); }
#pragma unroll
    for (int pf = 0; pf < 4; ++pf)
#pragma unroll
      for (int ff = 0; ff < 2; ++ff) {
        acc[pf][ff] = __builtin_amdgcn_mfma_f32_16x16x32_bf16(a_h[pf], b_h[ff], acc[pf][ff], 0, 0, 0);
        acc[pf][ff] = __builtin_amdgcn_mfma_f32_16x16x32_bf16(a_h[pf], b_l[ff], acc[pf][ff], 0, 0, 0);
        acc[pf][ff] = __builtin_amdgcn_mfma_f32_16x16x32_bf16(a_l[pf], b_h[ff], acc[pf][ff], 0, 0, 0);
      }
    __syncthreads();
    cur ^= 1;
  }
  // epilogue: row = m0+wr*64+pf*16+lg*4+reg, col = n0+wc*32+ff*16+lr
#pragma unroll
  for (int pf = 0; pf < 4; ++pf)
#pragma unroll
    for (int ff = 0; ff < 2; ++ff) {
      int col = n0 + wc*32 + ff*16 + lr;
      float bs = bias[col];
#pragma unroll
      for (int reg = 0; reg < 4; ++reg) {
        int row = m0 + wr*64 + pf*16 + lg*4 + reg;
        Cm[(size_t)row*Nc + col] = acc[pf][ff][reg] + bs;
      }
    }
#undef G_LOAD
#undef G_WRITE
}

// ---------------- prep: norms + layouts ----------------
__global__ __launch_bounds__(256) void prep2(const float* __restrict__ qkv,
                                             const float* __restrict__ temperature,
                                             float* __restrict__ Qb,
                                             float* __restrict__ KbT,
                                             ushort* __restrict__ VhT,
                                             ushort* __restrict__ VlT) {
  __shared__ float Ks[64*65];
  __shared__ float Vs[64*65];
  const int nb = blockIdx.x;        // 0..63
  const int h  = blockIdx.y;
  const int lane = threadIdx.x & 63;
  const int w = threadIdx.x >> 6;
  const float temp = temperature[h];
  const float CINV = 0.05103103630798288f;   // 384^-0.5
  const float S4   = 2.6321480259049848f;    // 48^0.25
  for (int r = 0; r < 16; ++r) {
    const int nl = w*16 + r;
    const int n  = nb*64 + nl;
    const float* row = qkv + (size_t)n * (3*CC) + h * DD;
    float qv = (lane < DD) ? row[lane] : 0.f;
    float kv = (lane < DD) ? row[CC + lane] : 0.f;
    float vv = (lane >= 1 && lane <= DD) ? row[2*CC + lane - 1] : 0.f;
    float qs = qv * CINV;
    float q2 = qs * qs;
    float k2 = kv * kv;
#pragma unroll
    for (int off = 32; off > 0; off >>= 1) {
      q2 += __shfl_xor(q2, off);
      k2 += __shfl_xor(k2, off);
    }
    float qn = qs / fmaxf(sqrtf(q2), 1e-12f) * (S4 * temp);
    float kn = kv / fmaxf(sqrtf(k2), 1e-12f) * S4;
    float qo = (lane < DD) ? qn : ((lane == DD) ? 6.928203230275509f : 0.f);
    float ko = (lane < DD) ? kn : ((lane == DD) ? 1.f : 0.f);
    float vo = (lane == 0) ? (1.f/NN) : ((lane <= DD) ? vv * (1.f/NN) : 0.f);
    Qb[((size_t)h * NN + n) * DP + lane] = qo;
    Ks[nl*65 + lane] = ko;
    Vs[nl*65 + lane] = vo;
  }
  __syncthreads();
  const int ch = threadIdx.x >> 2;
  const int q4 = threadIdx.x & 3;
  float kc[16], vc[16];
#pragma unroll
  for (int e = 0; e < 16; ++e) {
    int nl = q4*16 + e;
    kc[e] = Ks[nl*65 + ch];
    vc[e] = Vs[nl*65 + ch];
  }
  size_t tbase = ((size_t)h*64 + ch) * NN + nb*64 + q4*16;
#pragma unroll
  for (int e = 0; e < 16; e += 4)
    st4(KbT + tbase + e, make_float4(kc[e], kc[e+1], kc[e+2], kc[e+3]));
  uint hu[8], lu[8];
#pragma unroll
  for (int e = 0; e < 8; ++e) {
    float v0 = vc[2*e], v1 = vc[2*e+1];
    uint h0 = bf16rtn(v0), h1 = bf16rtn(v1);
    float d0 = v0 - __uint_as_float(h0 << 16);
    float d1 = v1 - __uint_as_float(h1 << 16);
    uint t0 = __float_as_uint(d0), t1 = __float_as_uint(d1);
    hu[e] = h0 | (h1 << 16);
    lu[e] = (t0 >> 16) | (t1 & 0xFFFF0000u);
  }
  *reinterpret_cast<uint4*>(VhT + tbase)     = make_uint4(hu[0],hu[1],hu[2],hu[3]);
  *reinterpret_cast<uint4*>(VhT + tbase + 8) = make_uint4(hu[4],hu[5],hu[6],hu[7]);
  *reinterpret_cast<uint4*>(VlT + tbase)     = make_uint4(lu[0],lu[1],lu[2],lu[3]);
  *reinterpret_cast<uint4*>(VlT + tbase + 8) = make_uint4(lu[4],lu[5],lu[6],lu[7]);
}

// ---------------- kvmod via MFMA (split bf16), XCD-pinned: h = bid&7 ----------
#define KST 40
#define KNST 36
__global__ __launch_bounds__(256) void kvmod_mfma(const float* __restrict__ KbT,
                                                  const ushort* __restrict__ VhT,
                                                  const ushort* __restrict__ VlT,
                                                  float* __restrict__ Mp) {
  __shared__ ushort KKh[256*KST];
  __shared__ ushort KKl[256*KST];
  __shared__ float  KnS[64*KNST];
  __shared__ ushort VhS[64*KST];
  __shared__ ushort VlS[64*KST];
  const int tid  = threadIdx.x;
  // XCD swizzle: dispatch maps wgid%8 -> XCD, so h = bid&7 pins each head's
  // K/V panel (~4 MB) to one XCD L2; the 5 p0-WGs sharing (h,part) co-reside.
  const int bid  = blockIdx.x;        // 0..319
  const int h    = bid & 7;
  const int idx  = bid >> 3;          // 0..39
  const int p0   = (idx % 5) * 256;
  const int part = idx / 5;
  const int nbase = part * 512;
  int ii = 63, jj = 63;
  {
    int pg = p0 + tid;
    if (pg < NPAIR) {
      int i = 0, rem = pg;
      while (rem >= 49 - i) { rem -= 49 - i; ++i; }
      ii = i; jj = i + rem;
    }
  }
  const float* krow_i = &KnS[ii*KNST];
  const float* krow_j = &KnS[jj*KNST];
  const int sch = tid >> 2;
  const int sq  = tid & 3;
  const size_t kgbase = ((size_t)h*64 + sch) * NN + nbase;
  const int lane = tid & 63, wv = tid >> 6;
  const int lr = lane & 15, lg = lane >> 4;
  f32x4 acc[4][4];
#pragma unroll
  for (int a = 0; a < 4; ++a)
#pragma unroll
    for (int b = 0; b < 4; ++b) acc[a][b] = (f32x4)0.f;

  for (int t = 0; t < 16; ++t) {
    const int k0 = t * 32;
    __syncthreads();
    {
      float4 a0 = ld4(KbT + kgbase + k0 + sq*8);
      float4 a1 = ld4(KbT + kgbase + k0 + sq*8 + 4);
      st4(&KnS[sch*KNST + sq*8], a0);
      st4(&KnS[sch*KNST + sq*8 + 4], a1);
      *reinterpret_cast<uint4*>(&VhS[sch*KST + sq*8]) =
          *reinterpret_cast<const uint4*>(VhT + kgbase + k0 + sq*8);
      *reinterpret_cast<uint4*>(&VlS[sch*KST + sq*8]) =
          *reinterpret_cast<const uint4*>(VlT + kgbase + k0 + sq*8);
    }
    __syncthreads();
    {
      uint hu[16], lu[16];
#pragma unroll
      for (int g = 0; g < 8; ++g) {
        float4 a = ld4(krow_i + g*4);
        float4 b = ld4(krow_j + g*4);
        float m0 = a.x*b.x, m1 = a.y*b.y, m2 = a.z*b.z, m3 = a.w*b.w;
        uint h0 = bf16rtn(m0), h1 = bf16rtn(m1), h2 = bf16rtn(m2), h3 = bf16rtn(m3);
        float d0 = m0 - __uint_as_float(h0 << 16);
        float d1 = m1 - __uint_as_float(h1 << 16);
        float d2 = m2 - __uint_as_float(h2 << 16);
        float d3 = m3 - __uint_as_float(h3 << 16);
        uint t0 = __float_as_uint(d0), t1 = __float_as_uint(d1);
        uint t2 = __float_as_uint(d2), t3 = __float_as_uint(d3);
        hu[2*g]   = h0 | (h1 << 16);
        hu[2*g+1] = h2 | (h3 << 16);
        lu[2*g]   = (t0 >> 16) | (t1 & 0xFFFF0000u);
        lu[2*g+1] = (t2 >> 16) | (t3 & 0xFFFF0000u);
      }
      uint4* dh = reinterpret_cast<uint4*>(&KKh[tid*KST]);
      uint4* dl = reinterpret_cast<uint4*>(&KKl[tid*KST]);
      dh[0] = make_uint4(hu[0],hu[1],hu[2],hu[3]);
      dh[1] = make_uint4(hu[4],hu[5],hu[6],hu[7]);
      dh[2] = make_uint4(hu[8],hu[9],hu[10],hu[11]);
      dh[3] = make_uint4(hu[12],hu[13],hu[14],hu[15]);
      dl[0] = make_uint4(lu[0],lu[1],lu[2],lu[3]);
      dl[1] = make_uint4(lu[4],lu[5],lu[6],lu[7]);
      dl[2] = make_uint4(lu[8],lu[9],lu[10],lu[11]);
      dl[3] = make_uint4(lu[12],lu[13],lu[14],lu[15]);
    }
    __syncthreads();
    short8 ah[4], al[4], bh[4], bl[4];
#pragma unroll
    for (int pf = 0; pf < 4; ++pf) {
      int prow = wv*64 + pf*16 + lr;
      ah[pf] = *reinterpret_cast<const short8*>(&KKh[prow*KST + lg*8]);
      al[pf] = *reinterpret_cast<const short8*>(&KKl[prow*KST + lg*8]);
    }
#pragma unroll
    for (int ff = 0; ff < 4; ++ff) {
      int frow = ff*16 + lr;
      bh[ff] = *reinterpret_cast<const short8*>(&VhS[frow*KST + lg*8]);
      bl[ff] = *reinterpret_cast<const short8*>(&VlS[frow*KST + lg*8]);
    }
#pragma unroll
    for (int pf = 0; pf < 4; ++pf)
#pragma unroll
      for (int ff = 0; ff < 4; ++ff) {
        acc[pf][ff] = __builtin_amdgcn_mfma_f32_16x16x32_bf16(ah[pf], bh[ff], acc[pf][ff], 0, 0, 0);
        acc[pf][ff] = __builtin_amdgcn_mfma_f32_16x16x32_bf16(ah[pf], bl[ff], acc[pf][ff], 0, 0, 0);
        acc[pf][ff] = __builtin_amdgcn_mfma_f32_16x16x32_bf16(al[pf], bh[ff], acc[pf][ff], 0, 0, 0);
      }
  }
  float* out = Mp + ((size_t)(part*HN + h) * PPAD + p0 + wv*64) * MPF;
#pragma unroll
  for (int pf = 0; pf < 4; ++pf)
#pragma unroll
    for (int ff = 0; ff < 4; ++ff) {
      int f = ff*16 + lr;
      if (f < MPF) {
#pragma unroll
        for (int reg = 0; reg < 4; ++reg) {
          int prow = pf*16 + lg*4 + reg;
          out[prow*MPF + f] = acc[pf][ff][reg];
        }
      }
    }
}

// ---------------- reduce parts + mirror into f-major bf16 slices ----------------
__global__ __launch_bounds__(256) void reduce_mirror(const float* __restrict__ Mp,
                                                     ushort* __restrict__ Mbh,
                                                     ushort* __restrict__ Mbl,
                                                     float* __restrict__ Mnorm) {
  const int pb = blockIdx.x;      // 0..19
  const int h  = blockIdx.y;
  const int pl = threadIdx.x & 63;
  const int fq0 = threadIdx.x >> 6;   // 0..3
  const int p = pb*64 + pl;
  if (p >= NPAIR) return;
  int i = 0, rem = p;
  while (rem >= 49 - i) { rem -= 49 - i; ++i; }
  const int j = i + rem;
  for (int fq = fq0; fq < 13; fq += 4) {
    float4 s = make_float4(0.f, 0.f, 0.f, 0.f);
#pragma unroll
    for (int part = 0; part < 8; ++part) {
      float4 a = ld4(Mp + ((size_t)(part*HN + h) * PPAD + p) * MPF + fq*4);
      s.x += a.x; s.y += a.y; s.z += a.z; s.w += a.w;
    }
    float sv[4] = {s.x, s.y, s.z, s.w};
#pragma unroll
    for (int c = 0; c < 4; ++c) {
      int f = fq*4 + c;
      float v = sv[c];
      uint hb = bf16rtn(v);
      float d = v - __uint_as_float(hb << 16);
      ushort lb = (ushort)(__float_as_uint(d) >> 16);
      size_t a1 = (((size_t)h*49 + i)*64 + f)*64 + j;
      size_t a2 = (((size_t)h*49 + j)*64 + f)*64 + i;
      Mbh[a1] = (ushort)hb; Mbl[a1] = lb;
      Mbh[a2] = (ushort)hb; Mbl[a2] = lb;
    }
    if (p == NPAIR-1) st4(&Mnorm[h*64 + fq*4], s);   // pair (48,48)
  }
}

// ---------------- y via MFMA, v6 = v4 structure + XCD pinning (h = bid&7) ----
// Per-head M (1.6 MB) fits one XCD's 4 MB L2 when all of head h's WGs land on
// XCD h (dispatch maps wgid%8 -> XCD). v4 internals unchanged (verified).
__global__ __launch_bounds__(256, 3) void y_mfma(const float* __restrict__ Qb,
                                                 const ushort* __restrict__ Mbh,
                                                 const ushort* __restrict__ Mbl,
                                                 float* __restrict__ Yp) {
  __shared__ float QT[28*128];
  __shared__ ushort Mt[2][2][32*64];  // [dbuf][hi/lo][frow*64 + slot*8]
  const int tid = threadIdx.x;
  const int bid = blockIdx.x;         // 0..1023
  const int h   = bid & 7;            // -> XCD h
  const int rest = bid >> 3;          // 0..127
  const int n0  = (rest & 31) * 128;
  const int z   = rest >> 5;          // 0..3
  const int zi = z >> 1;
  const int zf = z & 1;
  const int ibase = zi * 25;
  const int ni = zi ? 24 : 25;
  const int lane = tid & 63;
  const int wv = tid >> 6;
  const int lr = lane & 15, lg = lane >> 4;

  // ---- stage QT: channels [ibase, ibase+ni) transposed for 128 rows ----
  {
    const int ng = (ni + 3) >> 2;
    for (int v = tid; v < ng*128; v += 256) {
      int r = v & 127;
      int cg = v >> 7;
      float4 q = ld4(Qb + ((size_t)h*NN + n0 + r)*DP + ibase + cg*4);
      QT[(cg*4+0)*128 + r] = q.x;
      QT[(cg*4+1)*128 + r] = q.y;
      QT[(cg*4+2)*128 + r] = q.z;
      QT[(cg*4+3)*128 + r] = q.w;
    }
  }
  // ---- A-frags (constant): row = n0+wv*32+m*16+lr, k = kc*32+lg*8+e ----
  short8 ah[2][2], al[2][2];
#pragma unroll
  for (int m = 0; m < 2; ++m) {
    const float* qr = Qb + ((size_t)h*NN + n0 + wv*32 + m*16 + lr)*DP + lg*8;
#pragma unroll
    for (int kc = 0; kc < 2; ++kc) {
      float4 v0 = ld4(qr + kc*32);
      float4 v1 = ld4(qr + kc*32 + 4);
      float qv[8] = {v0.x,v0.y,v0.z,v0.w,v1.x,v1.y,v1.z,v1.w};
      union { uint u[4]; short8 s; } chh, cll;
#pragma unroll
      for (int e = 0; e < 4; ++e) {
        float x0 = qv[2*e], x1 = qv[2*e+1];
        uint h0 = bf16rtn(x0), h1 = bf16rtn(x1);
        float d0 = x0 - __uint_as_float(h0 << 16);
        float d1 = x1 - __uint_as_float(h1 << 16);
        chh.u[e] = h0 | (h1 << 16);
        cll.u[e] = (__float_as_uint(d0) >> 16) | (__float_as_uint(d1) & 0xFFFF0000u);
      }
      ah[m][kc] = chh.s;
      al[m][kc] = cll.s;
    }
  }
  // ---- half-slice staging: thread owns 32 B of one plane (2 chunks) ----
  const int sp   = tid >> 7;          // plane 0=hi 1=lo
  const int ss   = tid & 127;
  const int srow = ss >> 2;           // local f row 0..31
  const int sc2  = (ss & 3) * 2;      // chunk base 0,2,4,6
  const ushort* gsrc = (sp ? Mbl : Mbh) + (size_t)h*49*4096 + (zf*32 + srow)*64 + sc2*8;
  uint4 pre[2];
#define Y_LOAD(I) { const uint4* gp = reinterpret_cast<const uint4*>(gsrc + (size_t)(I)*4096); \
    pre[0] = gp[0]; pre[1] = gp[1]; }
#define Y_WRITE(BUF) { _Pragma("unroll") for (int e = 0; e < 2; ++e) { \
    int slot = (sc2 + e) ^ (srow & 7); \
    *reinterpret_cast<uint4*>(&Mt[BUF][sp][srow*64 + slot*8]) = pre[e]; } }

  Y_LOAD(ibase);
  Y_WRITE(0);
  Y_LOAD(ibase+1);

  f32x4 ya[2][2];
#pragma unroll
  for (int m = 0; m < 2; ++m)
#pragma unroll
    for (int ff = 0; ff < 2; ++ff) ya[m][ff] = (f32x4)0.f;

  int cur = 0;
  __syncthreads();
  for (int li = 0; li < ni; ++li) {
    // B-frags: local f row = ff*16+lr (0..31), slot = (kc*4+lg)^(row&7)
    short8 bh[2][2], bl[2][2];
#pragma unroll
    for (int kc = 0; kc < 2; ++kc)
#pragma unroll
      for (int ff = 0; ff < 2; ++ff) {
        int row = ff*16 + lr;
        int slot = (kc*4 + lg) ^ (row & 7);
        bh[kc][ff] = *reinterpret_cast<const short8*>(&Mt[cur][0][row*64 + slot*8]);
        bl[kc][ff] = *reinterpret_cast<const short8*>(&Mt[cur][1][row*64 + slot*8]);
      }
    if (li < ni-1) { Y_WRITE(cur^1); }
    if (li < ni-2) { Y_LOAD(ibase+li+2); }
#pragma unroll
    for (int m = 0; m < 2; ++m) {
      float4 qi = ld4(&QT[li*128 + wv*32 + m*16 + lg*4]);
#pragma unroll
      for (int ff = 0; ff < 2; ++ff) {
        f32x4 acc = (f32x4)0.f;
        acc = __builtin_amdgcn_mfma_f32_16x16x32_bf16(ah[m][0], bh[0][ff], acc, 0, 0, 0);
        acc = __builtin_amdgcn_mfma_f32_16x16x32_bf16(ah[m][0], bl[0][ff], acc, 0, 0, 0);
        acc = __builtin_amdgcn_mfma_f32_16x16x32_bf16(al[m][0], bh[0][ff], acc, 0, 0, 0);
        acc = __builtin_amdgcn_mfma_f32_16x16x32_bf16(ah[m][1], bh[1][ff], acc, 0, 0, 0);
        acc = __builtin_amdgcn_mfma_f32_16x16x32_bf16(ah[m][1], bl[1][ff], acc, 0, 0, 0);
        acc = __builtin_amdgcn_mfma_f32_16x16x32_bf16(al[m][1], bh[1][ff], acc, 0, 0, 0);
        ya[m][ff][0] += qi.x * acc[0];
        ya[m][ff][1] += qi.y * acc[1];
        ya[m][ff][2] += qi.z * acc[2];
        ya[m][ff][3] += qi.w * acc[3];
      }
    }
    __syncthreads();
    cur ^= 1;
  }
  // ---- write raw partials (disjoint f across zf; summed over zi by combine) ----
  float* out = Yp + ((size_t)(zi*HN + h) * NN) * 64;
#pragma unroll
  for (int m = 0; m < 2; ++m)
#pragma unroll
    for (int ff = 0; ff < 2; ++ff) {
      int f = zf*32 + ff*16 + lr;
#pragma unroll
      for (int reg = 0; reg < 4; ++reg) {
        int row = n0 + wv*32 + m*16 + lg*4 + reg;
        out[(size_t)row*64 + f] = ya[m][ff][reg];
      }
    }
#undef Y_LOAD
#undef Y_WRITE
}

// ---------------- combine partials -> split-bf16 attn planes ----------------
__global__ __launch_bounds__(256) void y_combine(const float* __restrict__ Yp,
                                                 const float* __restrict__ Mnorm,
                                                 ushort* __restrict__ AttnH,
                                                 ushort* __restrict__ AttnL) {
  const int h = blockIdx.y;
  const int t = threadIdx.x;
  const int r = blockIdx.x*64 + (t >> 2);
  const int fq = t & 3;
  const int lane = t & 63;
  const float* p0 = Yp + ((size_t)h*NN + r)*64 + fq*16;
  const float* p1 = Yp + ((size_t)(HN+h)*NN + r)*64 + fq*16;
  float y[16];
#pragma unroll
  for (int g = 0; g < 4; ++g) {
    float4 a = ld4(p0 + g*4);
    float4 b = ld4(p1 + g*4);
    float4 m = ld4(Mnorm + h*64 + fq*16 + g*4);
    y[g*4+0] = 0.5f*(a.x+b.x) + 24.f*m.x;
    y[g*4+1] = 0.5f*(a.y+b.y) + 24.f*m.y;
    y[g*4+2] = 0.5f*(a.z+b.z) + 24.f*m.z;
    y[g*4+3] = 0.5f*(a.w+b.w) + 24.f*m.w;
  }
  float y0 = __shfl(y[0], lane & ~3);
  float inv = 1.f / y0;
#pragma unroll
  for (int e = 0; e < 16; ++e) {
    int f = fq*16 + e;
    if (f >= 1 && f <= DD) {
      float o = y[e] * inv;
      uint hb = bf16rtn(o);
      float d = o - __uint_as_float(hb << 16);
      size_t a = (size_t)r*CC + h*DD + (f-1);
      AttnH[a] = (ushort)hb;
      AttnL[a] = (ushort)(__float_as_uint(d) >> 16);
    }
  }
}

extern "C" void kernel_launch(void* const* d_in, const int* in_sizes, int n_in,
                              void* d_out, int out_size, void* d_ws, size_t ws_size,
                              hipStream_t stream) {
  const float* x      = (const float*)d_in[0];
  const float* qkv_w  = (const float*)d_in[1];
  const float* qkv_b  = (const float*)d_in[2];
  const float* proj_w = (const float*)d_in[3];
  const float* proj_b = (const float*)d_in[4];
  const float* temp   = (const float*)d_in[5];
  float* ws = (float*)d_ws;

  // Region A [0, 4,718,592): qkv -> Mp -> Yp
  float*  qkv  = ws;
  float*  Mp   = ws;
  float*  Yp   = ws;
  // Region B: Qb
  float*  Qb   = ws + 4718592;
  // Region C [6,815,744, 8,912,896): Xh|Xl (split_x->gemm1) -> KbT (prep2->kvmod) -> Mbh|Mbl|Mnorm
  ushort* Xh   = (ushort*)(ws + 6815744);    // 1,572,864 us
  ushort* Xl   = Xh + 1572864;
  float*  KbT  = ws + 6815744;
  ushort* Mbh  = (ushort*)(ws + 6815744);
  ushort* Mbl  = Mbh + 1605632;
  float*  Mnorm= ws + 6815744 + 1605632;
  // Region D [8,912,896, 11,010,048): VhT|VlT (prep2->kvmod) -> AttnH|AttnL (y_combine->gemm2)
  ushort* VhT  = (ushort*)(ws + 8912896);
  ushort* VlT  = (ushort*)(ws + 9961472);
  ushort* AttnH= (ushort*)(ws + 8912896);
  ushort* AttnL= AttnH + 1572864;

  split_f32<<<1536, 256, 0, stream>>>(x, Xh, Xl, NN*CC/4);
  {
    dim3 g(1152/64, 4096/128);
    gemm_bf16<<<g, 256, 0, stream>>>(Xh, Xl, qkv_w, qkv_b, qkv, 4096, 1152, 384);
  }
  {
    dim3 g(64, HN);
    prep2<<<g, 256, 0, stream>>>(qkv, temp, Qb, KbT, VhT, VlT);
  }
  kvmod_mfma<<<320, 256, 0, stream>>>(KbT, VhT, VlT, Mp);
  hipMemsetAsync((void*)Mbh, 0, 2*(size_t)1605632*2 + 2048, stream);
  {
    dim3 g(PPAD/64, HN);
    reduce_mirror<<<g, 256, 0, stream>>>(Mp, Mbh, Mbl, Mnorm);
  }
  y_mfma<<<1024, 256, 0, stream>>>(Qb, Mbh, Mbl, Yp);
  {
    dim3 g(4096/64, HN);
    y_combine<<<g, 256, 0, stream>>>(Yp, Mnorm, AttnH, AttnL);
  }
  {
    dim3 g(384/64, 4096/128);
    gemm_bf16<<<g, 256, 0, stream>>>(AttnH, AttnL, proj_w, proj_b, (float*)d_out, 4096, 384, 384);
  }
}

// Round 11
// 201.411 us; speedup vs baseline: 1.1870x; 1.0077x over previous
//
#include <hip/hip_runtime.h>

#define HN 8
#define NN 4096
#define CC 384
#define DD 48
#define DP 64
#define NPAIR 1225   // (i<=j) over 49 channels
#define PPAD 1280
#define MPF 52       // f-padded row length of pair-major M

typedef unsigned short ushort;
typedef unsigned int uint;
typedef __attribute__((ext_vector_type(8))) short short8;
typedef __attribute__((ext_vector_type(4))) float f32x4;

__device__ __forceinline__ float4 ld4(const float* p){ return *reinterpret_cast<const float4*>(p); }
__device__ __forceinline__ void st4(float* p, const float4& v){ *reinterpret_cast<float4*>(p) = v; }

// Raw barrier: LDS visibility only (lgkmcnt), NO vmcnt drain — in-flight
// global->REGISTER prefetches legally cross (private dest, no cross-wave
// hazard). Compiler still inserts counted vmcnt at the reg consumption site.
#define RAW_BAR() asm volatile("s_waitcnt lgkmcnt(0)\ns_barrier" ::: "memory")

// RTN float->bf16 bits (inputs finite)
__device__ __forceinline__ uint bf16rtn(float x){
  uint u = __float_as_uint(x);
  return (u + 0x7FFFu + ((u >> 16) & 1u)) >> 16;
}

// ---------------- split fp32 -> bf16 hi/lo planes ----------------
__global__ __launch_bounds__(256) void split_f32(const float* __restrict__ in,
                                                 ushort* __restrict__ hi,
                                                 ushort* __restrict__ lo,
                                                 int n4) {
  int idx = blockIdx.x * 256 + threadIdx.x;
  if (idx >= n4) return;
  float4 v = ld4(in + (size_t)idx * 4);
  float bv[4] = {v.x, v.y, v.z, v.w};
  uint hu[2], lu[2];
#pragma unroll
  for (int e = 0; e < 2; ++e) {
    float x0 = bv[2*e], x1 = bv[2*e+1];
    uint h0 = bf16rtn(x0), h1 = bf16rtn(x1);
    float d0 = x0 - __uint_as_float(h0 << 16);
    float d1 = x1 - __uint_as_float(h1 << 16);
    hu[e] = h0 | (h1 << 16);
    lu[e] = (__float_as_uint(d0) >> 16) | (__float_as_uint(d1) & 0xFFFF0000u);
  }
  *reinterpret_cast<uint2*>(hi + (size_t)idx*4) = make_uint2(hu[0], hu[1]);
  *reinterpret_cast<uint2*>(lo + (size_t)idx*4) = make_uint2(lu[0], lu[1]);
}

// ---------------- MFMA NT GEMM (split bf16 A pre-split; B split on the fly) ----
// C[m][n] = sum_k A[m][k]*B[n][k] + bias[n]
#define GST 40   // ushort row stride in LDS (80 B): kvmod-proven bank spread
__global__ __launch_bounds__(256) void gemm_bf16(const ushort* __restrict__ Ah,
                                                 const ushort* __restrict__ Al,
                                                 const float*  __restrict__ Bw,
                                                 const float*  __restrict__ bias,
                                                 float* __restrict__ Cm,
                                                 int M, int Nc, int K) {
  __shared__ ushort AsH[2][128*GST], AsL[2][128*GST];
  __shared__ ushort BsH[2][64*GST],  BsL[2][64*GST];
  const int tid = threadIdx.x;
  const int n0 = blockIdx.x * 64;    // col-tile fastest: consecutive WGs share A panel
  const int m0 = blockIdx.y * 128;
  const int lane = tid & 63, wv = tid >> 6;
  const int wr = wv >> 1, wc = wv & 1;
  const int lr = lane & 15, lg = lane >> 4;
  const int ar = tid >> 1, ap = (tid & 1) << 4;   // A stage: row, 16-k half
  const int br = tid >> 2, bp = (tid & 3) << 3;   // B stage: row, 8-k quarter
  const ushort* gAh = Ah + (size_t)(m0 + ar) * K + ap;
  const ushort* gAl = Al + (size_t)(m0 + ar) * K + ap;
  const float*  gB  = Bw + (size_t)(n0 + br) * K + bp;
  uint4 rah0, rah1, ral0, ral1;
  float4 rb0, rb1;
#define G_LOAD(T) { int kk = (T)*32; \
    rah0 = *reinterpret_cast<const uint4*>(gAh + kk); \
    rah1 = *reinterpret_cast<const uint4*>(gAh + kk + 8); \
    ral0 = *reinterpret_cast<const uint4*>(gAl + kk); \
    ral1 = *reinterpret_cast<const uint4*>(gAl + kk + 8); \
    rb0 = ld4(gB + kk); rb1 = ld4(gB + kk + 4); }
#define G_WRITE(BUF) { \
    *reinterpret_cast<uint4*>(&AsH[BUF][ar*GST+ap])   = rah0; \
    *reinterpret_cast<uint4*>(&AsH[BUF][ar*GST+ap+8]) = rah1; \
    *reinterpret_cast<uint4*>(&AsL[BUF][ar*GST+ap])   = ral0; \
    *reinterpret_cast<uint4*>(&AsL[BUF][ar*GST+ap+8]) = ral1; \
    float bv[8] = {rb0.x,rb0.y,rb0.z,rb0.w,rb1.x,rb1.y,rb1.z,rb1.w}; \
    uint hu[4], lu[4]; \
    _Pragma("unroll") for (int e = 0; e < 4; ++e) { \
      float x0 = bv[2*e], x1 = bv[2*e+1]; \
      uint h0 = bf16rtn(x0), h1 = bf16rtn(x1); \
      float d0 = x0 - __uint_as_float(h0 << 16); \
      float d1 = x1 - __uint_as_float(h1 << 16); \
      hu[e] = h0 | (h1 << 16); \
      lu[e] = (__float_as_uint(d0) >> 16) | (__float_as_uint(d1) & 0xFFFF0000u); } \
    *reinterpret_cast<uint4*>(&BsH[BUF][br*GST+bp]) = make_uint4(hu[0],hu[1],hu[2],hu[3]); \
    *reinterpret_cast<uint4*>(&BsL[BUF][br*GST+bp]) = make_uint4(lu[0],lu[1],lu[2],lu[3]); }

  f32x4 acc[4][2];
#pragma unroll
  for (int pf = 0; pf < 4; ++pf)
#pragma unroll
    for (int ff = 0; ff < 2; ++ff) acc[pf][ff] = (f32x4)0.f;

  G_LOAD(0);
  G_WRITE(0);
  G_LOAD(1);
  const int NT = K / 32;
  int cur = 0;
  RAW_BAR();
  for (int t = 0; t < NT; ++t) {
    short8 a_h[4], a_l[4], b_h[2], b_l[2];
#pragma unroll
    for (int pf = 0; pf < 4; ++pf) {
      int row = wr*64 + pf*16 + lr;
      a_h[pf] = *reinterpret_cast<const short8*>(&AsH[cur][row*GST + lg*8]);
      a_l[pf] = *reinterpret_cast<const short8*>(&AsL[cur][row*GST + lg*8]);
    }
#pragma unroll
    for (int ff = 0; ff < 2; ++ff) {
      int col = wc*32 + ff*16 + lr;
      b_h[ff] = *reinterpret_cast<const short8*>(&BsH[cur][col*GST + lg*8]);
      b_l[ff] = *reinterpret_cast<const short8*>(&BsL[cur][col*GST + lg*8]);
    }
    if (t < NT-1) { G_WRITE(cur^1); }
    if (t < NT-2) { G_LOAD(t+2); }
#pragma unroll
    for (int pf = 0; pf < 4; ++pf)
#pragma unroll
      for (int ff = 0; ff < 2; ++ff) {
        acc[pf][ff] = __builtin_amdgcn_mfma_f32_16x16x32_bf16(a_h[pf], b_h[ff], acc[pf][ff], 0, 0, 0);
        acc[pf][ff] = __builtin_amdgcn_mfma_f32_16x16x32_bf16(a_h[pf], b_l[ff], acc[pf][ff], 0, 0, 0);
        acc[pf][ff] = __builtin_amdgcn_mfma_f32_16x16x32_bf16(a_l[pf], b_h[ff], acc[pf][ff], 0, 0, 0);
      }
    RAW_BAR();
    cur ^= 1;
  }
  // epilogue: row = m0+wr*64+pf*16+lg*4+reg, col = n0+wc*32+ff*16+lr
#pragma unroll
  for (int pf = 0; pf < 4; ++pf)
#pragma unroll
    for (int ff = 0; ff < 2; ++ff) {
      int col = n0 + wc*32 + ff*16 + lr;
      float bs = bias[col];
#pragma unroll
      for (int reg = 0; reg < 4; ++reg) {
        int row = m0 + wr*64 + pf*16 + lg*4 + reg;
        Cm[(size_t)row*Nc + col] = acc[pf][ff][reg] + bs;
      }
    }
#undef G_LOAD
#undef G_WRITE
}

// ---------------- prep: norms + layouts ----------------
__global__ __launch_bounds__(256) void prep2(const float* __restrict__ qkv,
                                             const float* __restrict__ temperature,
                                             float* __restrict__ Qb,
                                             float* __restrict__ KbT,
                                             ushort* __restrict__ VhT,
                                             ushort* __restrict__ VlT) {
  __shared__ float Ks[64*65];
  __shared__ float Vs[64*65];
  const int nb = blockIdx.x;        // 0..63
  const int h  = blockIdx.y;
  const int lane = threadIdx.x & 63;
  const int w = threadIdx.x >> 6;
  const float temp = temperature[h];
  const float CINV = 0.05103103630798288f;   // 384^-0.5
  const float S4   = 2.6321480259049848f;    // 48^0.25
  for (int r = 0; r < 16; ++r) {
    const int nl = w*16 + r;
    const int n  = nb*64 + nl;
    const float* row = qkv + (size_t)n * (3*CC) + h * DD;
    float qv = (lane < DD) ? row[lane] : 0.f;
    float kv = (lane < DD) ? row[CC + lane] : 0.f;
    float vv = (lane >= 1 && lane <= DD) ? row[2*CC + lane - 1] : 0.f;
    float qs = qv * CINV;
    float q2 = qs * qs;
    float k2 = kv * kv;
#pragma unroll
    for (int off = 32; off > 0; off >>= 1) {
      q2 += __shfl_xor(q2, off);
      k2 += __shfl_xor(k2, off);
    }
    float qn = qs / fmaxf(sqrtf(q2), 1e-12f) * (S4 * temp);
    float kn = kv / fmaxf(sqrtf(k2), 1e-12f) * S4;
    float qo = (lane < DD) ? qn : ((lane == DD) ? 6.928203230275509f : 0.f);
    float ko = (lane < DD) ? kn : ((lane == DD) ? 1.f : 0.f);
    float vo = (lane == 0) ? (1.f/NN) : ((lane <= DD) ? vv * (1.f/NN) : 0.f);
    Qb[((size_t)h * NN + n) * DP + lane] = qo;
    Ks[nl*65 + lane] = ko;
    Vs[nl*65 + lane] = vo;
  }
  __syncthreads();
  const int ch = threadIdx.x >> 2;
  const int q4 = threadIdx.x & 3;
  float kc[16], vc[16];
#pragma unroll
  for (int e = 0; e < 16; ++e) {
    int nl = q4*16 + e;
    kc[e] = Ks[nl*65 + ch];
    vc[e] = Vs[nl*65 + ch];
  }
  size_t tbase = ((size_t)h*64 + ch) * NN + nb*64 + q4*16;
#pragma unroll
  for (int e = 0; e < 16; e += 4)
    st4(KbT + tbase + e, make_float4(kc[e], kc[e+1], kc[e+2], kc[e+3]));
  uint hu[8], lu[8];
#pragma unroll
  for (int e = 0; e < 8; ++e) {
    float v0 = vc[2*e], v1 = vc[2*e+1];
    uint h0 = bf16rtn(v0), h1 = bf16rtn(v1);
    float d0 = v0 - __uint_as_float(h0 << 16);
    float d1 = v1 - __uint_as_float(h1 << 16);
    uint t0 = __float_as_uint(d0), t1 = __float_as_uint(d1);
    hu[e] = h0 | (h1 << 16);
    lu[e] = (t0 >> 16) | (t1 & 0xFFFF0000u);
  }
  *reinterpret_cast<uint4*>(VhT + tbase)     = make_uint4(hu[0],hu[1],hu[2],hu[3]);
  *reinterpret_cast<uint4*>(VhT + tbase + 8) = make_uint4(hu[4],hu[5],hu[6],hu[7]);
  *reinterpret_cast<uint4*>(VlT + tbase)     = make_uint4(lu[0],lu[1],lu[2],lu[3]);
  *reinterpret_cast<uint4*>(VlT + tbase + 8) = make_uint4(lu[4],lu[5],lu[6],lu[7]);
}

// ---------------- kvmod via MFMA (split bf16), XCD-pinned, T14 prefetch ------
#define KST 40
#define KNST 36
__global__ __launch_bounds__(256) void kvmod_mfma(const float* __restrict__ KbT,
                                                  const ushort* __restrict__ VhT,
                                                  const ushort* __restrict__ VlT,
                                                  float* __restrict__ Mp) {
  __shared__ ushort KKh[256*KST];
  __shared__ ushort KKl[256*KST];
  __shared__ float  KnS[64*KNST];
  __shared__ ushort VhS[64*KST];
  __shared__ ushort VlS[64*KST];
  const int tid  = threadIdx.x;
  const int bid  = blockIdx.x;        // 0..319 ; h = bid&7 pins head to XCD
  const int h    = bid & 7;
  const int idx  = bid >> 3;          // 0..39
  const int p0   = (idx % 5) * 256;
  const int part = idx / 5;
  const int nbase = part * 512;
  int ii = 63, jj = 63;
  {
    int pg = p0 + tid;
    if (pg < NPAIR) {
      int i = 0, rem = pg;
      while (rem >= 49 - i) { rem -= 49 - i; ++i; }
      ii = i; jj = i + rem;
    }
  }
  const float* krow_i = &KnS[ii*KNST];
  const float* krow_j = &KnS[jj*KNST];
  const int sch = tid >> 2;
  const int sq  = tid & 3;
  const size_t kgbase = ((size_t)h*64 + sch) * NN + nbase;
  const int lane = tid & 63, wv = tid >> 6;
  const int lr = lane & 15, lg = lane >> 4;
  f32x4 acc[4][4];
#pragma unroll
  for (int a = 0; a < 4; ++a)
#pragma unroll
    for (int b = 0; b < 4; ++b) acc[a][b] = (f32x4)0.f;

  // T14 split: issue global loads early (regs), LDS-write after the barrier.
  float4 pa0, pa1; uint4 pvh, pvl;
#define PRE_LOAD(T) { int k0_ = (T)*32; \
    pa0 = ld4(KbT + kgbase + k0_ + sq*8); \
    pa1 = ld4(KbT + kgbase + k0_ + sq*8 + 4); \
    pvh = *reinterpret_cast<const uint4*>(VhT + kgbase + k0_ + sq*8); \
    pvl = *reinterpret_cast<const uint4*>(VlT + kgbase + k0_ + sq*8); }
#define STAGE_WRITE() { \
    st4(&KnS[sch*KNST + sq*8], pa0); \
    st4(&KnS[sch*KNST + sq*8 + 4], pa1); \
    *reinterpret_cast<uint4*>(&VhS[sch*KST + sq*8]) = pvh; \
    *reinterpret_cast<uint4*>(&VlS[sch*KST + sq*8]) = pvl; }

  PRE_LOAD(0);
  for (int t = 0; t < 16; ++t) {
    RAW_BAR();                 // prev iteration's LDS readers done
    STAGE_WRITE();
    if (t < 15) { PRE_LOAD(t+1); }   // in flight across the next two phases
    RAW_BAR();                 // stage visible
    {
      uint hu[16], lu[16];
#pragma unroll
      for (int g = 0; g < 8; ++g) {
        float4 a = ld4(krow_i + g*4);
        float4 b = ld4(krow_j + g*4);
        float m0 = a.x*b.x, m1 = a.y*b.y, m2 = a.z*b.z, m3 = a.w*b.w;
        uint h0 = bf16rtn(m0), h1 = bf16rtn(m1), h2 = bf16rtn(m2), h3 = bf16rtn(m3);
        float d0 = m0 - __uint_as_float(h0 << 16);
        float d1 = m1 - __uint_as_float(h1 << 16);
        float d2 = m2 - __uint_as_float(h2 << 16);
        float d3 = m3 - __uint_as_float(h3 << 16);
        uint t0 = __float_as_uint(d0), t1 = __float_as_uint(d1);
        uint t2 = __float_as_uint(d2), t3 = __float_as_uint(d3);
        hu[2*g]   = h0 | (h1 << 16);
        hu[2*g+1] = h2 | (h3 << 16);
        lu[2*g]   = (t0 >> 16) | (t1 & 0xFFFF0000u);
        lu[2*g+1] = (t2 >> 16) | (t3 & 0xFFFF0000u);
      }
      uint4* dh = reinterpret_cast<uint4*>(&KKh[tid*KST]);
      uint4* dl = reinterpret_cast<uint4*>(&KKl[tid*KST]);
      dh[0] = make_uint4(hu[0],hu[1],hu[2],hu[3]);
      dh[1] = make_uint4(hu[4],hu[5],hu[6],hu[7]);
      dh[2] = make_uint4(hu[8],hu[9],hu[10],hu[11]);
      dh[3] = make_uint4(hu[12],hu[13],hu[14],hu[15]);
      dl[0] = make_uint4(lu[0],lu[1],lu[2],lu[3]);
      dl[1] = make_uint4(lu[4],lu[5],lu[6],lu[7]);
      dl[2] = make_uint4(lu[8],lu[9],lu[10],lu[11]);
      dl[3] = make_uint4(lu[12],lu[13],lu[14],lu[15]);
    }
    RAW_BAR();                 // KK visible
    short8 ah[4], al[4], bh[4], bl[4];
#pragma unroll
    for (int pf = 0; pf < 4; ++pf) {
      int prow = wv*64 + pf*16 + lr;
      ah[pf] = *reinterpret_cast<const short8*>(&KKh[prow*KST + lg*8]);
      al[pf] = *reinterpret_cast<const short8*>(&KKl[prow*KST + lg*8]);
    }
#pragma unroll
    for (int ff = 0; ff < 4; ++ff) {
      int frow = ff*16 + lr;
      bh[ff] = *reinterpret_cast<const short8*>(&VhS[frow*KST + lg*8]);
      bl[ff] = *reinterpret_cast<const short8*>(&VlS[frow*KST + lg*8]);
    }
#pragma unroll
    for (int pf = 0; pf < 4; ++pf)
#pragma unroll
      for (int ff = 0; ff < 4; ++ff) {
        acc[pf][ff] = __builtin_amdgcn_mfma_f32_16x16x32_bf16(ah[pf], bh[ff], acc[pf][ff], 0, 0, 0);
        acc[pf][ff] = __builtin_amdgcn_mfma_f32_16x16x32_bf16(ah[pf], bl[ff], acc[pf][ff], 0, 0, 0);
        acc[pf][ff] = __builtin_amdgcn_mfma_f32_16x16x32_bf16(al[pf], bh[ff], acc[pf][ff], 0, 0, 0);
      }
  }
  float* out = Mp + ((size_t)(part*HN + h) * PPAD + p0 + wv*64) * MPF;
#pragma unroll
  for (int pf = 0; pf < 4; ++pf)
#pragma unroll
    for (int ff = 0; ff < 4; ++ff) {
      int f = ff*16 + lr;
      if (f < MPF) {
#pragma unroll
        for (int reg = 0; reg < 4; ++reg) {
          int prow = pf*16 + lg*4 + reg;
          out[prow*MPF + f] = acc[pf][ff][reg];
        }
      }
    }
#undef PRE_LOAD
#undef STAGE_WRITE
}

// ---------------- reduce parts + mirror into f-major bf16 slices ----------------
__global__ __launch_bounds__(256) void reduce_mirror(const float* __restrict__ Mp,
                                                     ushort* __restrict__ Mbh,
                                                     ushort* __restrict__ Mbl,
                                                     float* __restrict__ Mnorm) {
  const int pb = blockIdx.x;      // 0..19
  const int h  = blockIdx.y;
  const int pl = threadIdx.x & 63;
  const int fq0 = threadIdx.x >> 6;   // 0..3
  const int p = pb*64 + pl;
  if (p >= NPAIR) return;
  int i = 0, rem = p;
  while (rem >= 49 - i) { rem -= 49 - i; ++i; }
  const int j = i + rem;
  for (int fq = fq0; fq < 13; fq += 4) {
    float4 s = make_float4(0.f, 0.f, 0.f, 0.f);
#pragma unroll
    for (int part = 0; part < 8; ++part) {
      float4 a = ld4(Mp + ((size_t)(part*HN + h) * PPAD + p) * MPF + fq*4);
      s.x += a.x; s.y += a.y; s.z += a.z; s.w += a.w;
    }
    float sv[4] = {s.x, s.y, s.z, s.w};
#pragma unroll
    for (int c = 0; c < 4; ++c) {
      int f = fq*4 + c;
      float v = sv[c];
      uint hb = bf16rtn(v);
      float d = v - __uint_as_float(hb << 16);
      ushort lb = (ushort)(__float_as_uint(d) >> 16);
      size_t a1 = (((size_t)h*49 + i)*64 + f)*64 + j;
      size_t a2 = (((size_t)h*49 + j)*64 + f)*64 + i;
      Mbh[a1] = (ushort)hb; Mbl[a1] = lb;
      Mbh[a2] = (ushort)hb; Mbl[a2] = lb;
    }
    if (p == NPAIR-1) st4(&Mnorm[h*64 + fq*4], s);   // pair (48,48)
  }
}

// ---------------- y via MFMA, v7 = v6 + raw barriers (no vmcnt drain) --------
__global__ __launch_bounds__(256, 3) void y_mfma(const float* __restrict__ Qb,
                                                 const ushort* __restrict__ Mbh,
                                                 const ushort* __restrict__ Mbl,
                                                 float* __restrict__ Yp) {
  __shared__ float QT[28*128];
  __shared__ ushort Mt[2][2][32*64];  // [dbuf][hi/lo][frow*64 + slot*8]
  const int tid = threadIdx.x;
  const int bid = blockIdx.x;         // 0..1023
  const int h   = bid & 7;            // -> XCD h
  const int rest = bid >> 3;          // 0..127
  const int n0  = (rest & 31) * 128;
  const int z   = rest >> 5;          // 0..3
  const int zi = z >> 1;
  const int zf = z & 1;
  const int ibase = zi * 25;
  const int ni = zi ? 24 : 25;
  const int lane = tid & 63;
  const int wv = tid >> 6;
  const int lr = lane & 15, lg = lane >> 4;

  // ---- stage QT: channels [ibase, ibase+ni) transposed for 128 rows ----
  {
    const int ng = (ni + 3) >> 2;
    for (int v = tid; v < ng*128; v += 256) {
      int r = v & 127;
      int cg = v >> 7;
      float4 q = ld4(Qb + ((size_t)h*NN + n0 + r)*DP + ibase + cg*4);
      QT[(cg*4+0)*128 + r] = q.x;
      QT[(cg*4+1)*128 + r] = q.y;
      QT[(cg*4+2)*128 + r] = q.z;
      QT[(cg*4+3)*128 + r] = q.w;
    }
  }
  // ---- A-frags (constant): row = n0+wv*32+m*16+lr, k = kc*32+lg*8+e ----
  short8 ah[2][2], al[2][2];
#pragma unroll
  for (int m = 0; m < 2; ++m) {
    const float* qr = Qb + ((size_t)h*NN + n0 + wv*32 + m*16 + lr)*DP + lg*8;
#pragma unroll
    for (int kc = 0; kc < 2; ++kc) {
      float4 v0 = ld4(qr + kc*32);
      float4 v1 = ld4(qr + kc*32 + 4);
      float qv[8] = {v0.x,v0.y,v0.z,v0.w,v1.x,v1.y,v1.z,v1.w};
      union { uint u[4]; short8 s; } chh, cll;
#pragma unroll
      for (int e = 0; e < 4; ++e) {
        float x0 = qv[2*e], x1 = qv[2*e+1];
        uint h0 = bf16rtn(x0), h1 = bf16rtn(x1);
        float d0 = x0 - __uint_as_float(h0 << 16);
        float d1 = x1 - __uint_as_float(h1 << 16);
        chh.u[e] = h0 | (h1 << 16);
        cll.u[e] = (__float_as_uint(d0) >> 16) | (__float_as_uint(d1) & 0xFFFF0000u);
      }
      ah[m][kc] = chh.s;
      al[m][kc] = cll.s;
    }
  }
  // ---- half-slice staging: thread owns 32 B of one plane (2 chunks) ----
  const int sp   = tid >> 7;          // plane 0=hi 1=lo
  const int ss   = tid & 127;
  const int srow = ss >> 2;           // local f row 0..31
  const int sc2  = (ss & 3) * 2;      // chunk base 0,2,4,6
  const ushort* gsrc = (sp ? Mbl : Mbh) + (size_t)h*49*4096 + (zf*32 + srow)*64 + sc2*8;
  uint4 pre[2];
#define Y_LOAD(I) { const uint4* gp = reinterpret_cast<const uint4*>(gsrc + (size_t)(I)*4096); \
    pre[0] = gp[0]; pre[1] = gp[1]; }
#define Y_WRITE(BUF) { _Pragma("unroll") for (int e = 0; e < 2; ++e) { \
    int slot = (sc2 + e) ^ (srow & 7); \
    *reinterpret_cast<uint4*>(&Mt[BUF][sp][srow*64 + slot*8]) = pre[e]; } }

  Y_LOAD(ibase);
  Y_WRITE(0);
  Y_LOAD(ibase+1);

  f32x4 ya[2][2];
#pragma unroll
  for (int m = 0; m < 2; ++m)
#pragma unroll
    for (int ff = 0; ff < 2; ++ff) ya[m][ff] = (f32x4)0.f;

  int cur = 0;
  RAW_BAR();
  for (int li = 0; li < ni; ++li) {
    // B-frags: local f row = ff*16+lr (0..31), slot = (kc*4+lg)^(row&7)
    short8 bh[2][2], bl[2][2];
#pragma unroll
    for (int kc = 0; kc < 2; ++kc)
#pragma unroll
      for (int ff = 0; ff < 2; ++ff) {
        int row = ff*16 + lr;
        int slot = (kc*4 + lg) ^ (row & 7);
        bh[kc][ff] = *reinterpret_cast<const short8*>(&Mt[cur][0][row*64 + slot*8]);
        bl[kc][ff] = *reinterpret_cast<const short8*>(&Mt[cur][1][row*64 + slot*8]);
      }
    if (li < ni-1) { Y_WRITE(cur^1); }
    if (li < ni-2) { Y_LOAD(ibase+li+2); }
#pragma unroll
    for (int m = 0; m < 2; ++m) {
      float4 qi = ld4(&QT[li*128 + wv*32 + m*16 + lg*4]);
#pragma unroll
      for (int ff = 0; ff < 2; ++ff) {
        f32x4 acc = (f32x4)0.f;
        acc = __builtin_amdgcn_mfma_f32_16x16x32_bf16(ah[m][0], bh[0][ff], acc, 0, 0, 0);
        acc = __builtin_amdgcn_mfma_f32_16x16x32_bf16(ah[m][0], bl[0][ff], acc, 0, 0, 0);
        acc = __builtin_amdgcn_mfma_f32_16x16x32_bf16(al[m][0], bh[0][ff], acc, 0, 0, 0);
        acc = __builtin_amdgcn_mfma_f32_16x16x32_bf16(ah[m][1], bh[1][ff], acc, 0, 0, 0);
        acc = __builtin_amdgcn_mfma_f32_16x16x32_bf16(ah[m][1], bl[1][ff], acc, 0, 0, 0);
        acc = __builtin_amdgcn_mfma_f32_16x16x32_bf16(al[m][1], bh[1][ff], acc, 0, 0, 0);
        ya[m][ff][0] += qi.x * acc[0];
        ya[m][ff][1] += qi.y * acc[1];
        ya[m][ff][2] += qi.z * acc[2];
        ya[m][ff][3] += qi.w * acc[3];
      }
    }
    RAW_BAR();
    cur ^= 1;
  }
  // ---- write raw partials (disjoint f across zf; summed over zi by combine) ----
  float* out = Yp + ((size_t)(zi*HN + h) * NN) * 64;
#pragma unroll
  for (int m = 0; m < 2; ++m)
#pragma unroll
    for (int ff = 0; ff < 2; ++ff) {
      int f = zf*32 + ff*16 + lr;
#pragma unroll
      for (int reg = 0; reg < 4; ++reg) {
        int row = n0 + wv*32 + m*16 + lg*4 + reg;
        out[(size_t)row*64 + f] = ya[m][ff][reg];
      }
    }
#undef Y_LOAD
#undef Y_WRITE
}

// ---------------- combine partials -> split-bf16 attn planes ----------------
__global__ __launch_bounds__(256) void y_combine(const float* __restrict__ Yp,
                                                 const float* __restrict__ Mnorm,
                                                 ushort* __restrict__ AttnH,
                                                 ushort* __restrict__ AttnL) {
  const int h = blockIdx.y;
  const int t = threadIdx.x;
  const int r = blockIdx.x*64 + (t >> 2);
  const int fq = t & 3;
  const int lane = t & 63;
  const float* p0 = Yp + ((size_t)h*NN + r)*64 + fq*16;
  const float* p1 = Yp + ((size_t)(HN+h)*NN + r)*64 + fq*16;
  float y[16];
#pragma unroll
  for (int g = 0; g < 4; ++g) {
    float4 a = ld4(p0 + g*4);
    float4 b = ld4(p1 + g*4);
    float4 m = ld4(Mnorm + h*64 + fq*16 + g*4);
    y[g*4+0] = 0.5f*(a.x+b.x) + 24.f*m.x;
    y[g*4+1] = 0.5f*(a.y+b.y) + 24.f*m.y;
    y[g*4+2] = 0.5f*(a.z+b.z) + 24.f*m.z;
    y[g*4+3] = 0.5f*(a.w+b.w) + 24.f*m.w;
  }
  float y0 = __shfl(y[0], lane & ~3);
  float inv = 1.f / y0;
#pragma unroll
  for (int e = 0; e < 16; ++e) {
    int f = fq*16 + e;
    if (f >= 1 && f <= DD) {
      float o = y[e] * inv;
      uint hb = bf16rtn(o);
      float d = o - __uint_as_float(hb << 16);
      size_t a = (size_t)r*CC + h*DD + (f-1);
      AttnH[a] = (ushort)hb;
      AttnL[a] = (ushort)(__float_as_uint(d) >> 16);
    }
  }
}

extern "C" void kernel_launch(void* const* d_in, const int* in_sizes, int n_in,
                              void* d_out, int out_size, void* d_ws, size_t ws_size,
                              hipStream_t stream) {
  const float* x      = (const float*)d_in[0];
  const float* qkv_w  = (const float*)d_in[1];
  const float* qkv_b  = (const float*)d_in[2];
  const float* proj_w = (const float*)d_in[3];
  const float* proj_b = (const float*)d_in[4];
  const float* temp   = (const float*)d_in[5];
  float* ws = (float*)d_ws;

  // Region A [0, 4,718,592): qkv -> Mp -> Yp
  float*  qkv  = ws;
  float*  Mp   = ws;
  float*  Yp   = ws;
  // Region B: Qb
  float*  Qb   = ws + 4718592;
  // Region C [6,815,744, 8,912,896): Xh|Xl (split_x->gemm1) -> KbT (prep2->kvmod) -> Mbh|Mbl|Mnorm
  ushort* Xh   = (ushort*)(ws + 6815744);    // 1,572,864 us
  ushort* Xl   = Xh + 1572864;
  float*  KbT  = ws + 6815744;
  ushort* Mbh  = (ushort*)(ws + 6815744);
  ushort* Mbl  = Mbh + 1605632;
  float*  Mnorm= ws + 6815744 + 1605632;
  // Region D [8,912,896, 11,010,048): VhT|VlT (prep2->kvmod) -> AttnH|AttnL (y_combine->gemm2)
  ushort* VhT  = (ushort*)(ws + 8912896);
  ushort* VlT  = (ushort*)(ws + 9961472);
  ushort* AttnH= (ushort*)(ws + 8912896);
  ushort* AttnL= AttnH + 1572864;

  split_f32<<<1536, 256, 0, stream>>>(x, Xh, Xl, NN*CC/4);
  {
    dim3 g(1152/64, 4096/128);
    gemm_bf16<<<g, 256, 0, stream>>>(Xh, Xl, qkv_w, qkv_b, qkv, 4096, 1152, 384);
  }
  {
    dim3 g(64, HN);
    prep2<<<g, 256, 0, stream>>>(qkv, temp, Qb, KbT, VhT, VlT);
  }
  kvmod_mfma<<<320, 256, 0, stream>>>(KbT, VhT, VlT, Mp);
  hipMemsetAsync((void*)Mbh, 0, 2*(size_t)1605632*2 + 2048, stream);
  {
    dim3 g(PPAD/64, HN);
    reduce_mirror<<<g, 256, 0, stream>>>(Mp, Mbh, Mbl, Mnorm);
  }
  y_mfma<<<1024, 256, 0, stream>>>(Qb, Mbh, Mbl, Yp);
  {
    dim3 g(4096/64, HN);
    y_combine<<<g, 256, 0, stream>>>(Yp, Mnorm, AttnH, AttnL);
  }
  {
    dim3 g(384/64, 4096/128);
    gemm_bf16<<<g, 256, 0, stream>>>(AttnH, AttnL, proj_w, proj_b, (float*)d_out, 4096, 384, 384);
  }
}

// Round 12
// 178.466 us; speedup vs baseline: 1.3396x; 1.1286x over previous
//
#include <hip/hip_runtime.h>

#define HN 8
#define NN 4096
#define CC 384
#define DD 48
#define DP 64
#define NPAIR 1225   // (i<=j) over 49 channels (old triangle enumeration, kvmod/Mp)
#define PPAD 1280
#define MPF 52       // f-padded row length of pair-major Mp
#define NP2 1792     // new aligned-chunk pair count (224 chunks of 8)
#define QRS 68       // Qrow stride (272 B: 16B-aligned rows, 2-way banks)

typedef unsigned short ushort;
typedef unsigned int uint;
typedef __attribute__((ext_vector_type(8))) short short8;
typedef __attribute__((ext_vector_type(4))) float f32x4;

__device__ __forceinline__ float4 ld4(const float* p){ return *reinterpret_cast<const float4*>(p); }
__device__ __forceinline__ void st4(float* p, const float4& v){ *reinterpret_cast<float4*>(p) = v; }

// Raw barrier: LDS visibility only; in-flight global->REG prefetch crosses.
#define RAW_BAR() asm volatile("s_waitcnt lgkmcnt(0)\ns_barrier" ::: "memory")

// RTN float->bf16 bits (inputs finite)
__device__ __forceinline__ uint bf16rtn(float x){
  uint u = __float_as_uint(x);
  return (u + 0x7FFFu + ((u >> 16) & 1u)) >> 16;
}

// chunk c (0..223) -> (i, jb): chunk covers pairs (i, jb*8+e), e=0..7.
// Blocks of 8 i's; i-block b has (7-b) j-blocks (jb = b..6).
__device__ __forceinline__ void chunk_ij(int c, int& i, int& jb){
  if (c < 56)       { i = c/7;            jb = c%7; }
  else if (c < 104) { int t=c-56;  i = 8  + t/6; jb = 1 + t%6; }
  else if (c < 144) { int t=c-104; i = 16 + t/5; jb = 2 + t%5; }
  else if (c < 176) { int t=c-144; i = 24 + t/4; jb = 3 + t%4; }
  else if (c < 200) { int t=c-176; i = 32 + t/3; jb = 4 + t%3; }
  else if (c < 216) { int t=c-200; i = 40 + t/2; jb = 5 + t%2; }
  else              { i = 48 + (c-216);   jb = 6; }
}

// ---------------- split fp32 -> bf16 hi/lo planes ----------------
__global__ __launch_bounds__(256) void split_f32(const float* __restrict__ in,
                                                 ushort* __restrict__ hi,
                                                 ushort* __restrict__ lo,
                                                 int n4) {
  int idx = blockIdx.x * 256 + threadIdx.x;
  if (idx >= n4) return;
  float4 v = ld4(in + (size_t)idx * 4);
  float bv[4] = {v.x, v.y, v.z, v.w};
  uint hu[2], lu[2];
#pragma unroll
  for (int e = 0; e < 2; ++e) {
    float x0 = bv[2*e], x1 = bv[2*e+1];
    uint h0 = bf16rtn(x0), h1 = bf16rtn(x1);
    float d0 = x0 - __uint_as_float(h0 << 16);
    float d1 = x1 - __uint_as_float(h1 << 16);
    hu[e] = h0 | (h1 << 16);
    lu[e] = (__float_as_uint(d0) >> 16) | (__float_as_uint(d1) & 0xFFFF0000u);
  }
  *reinterpret_cast<uint2*>(hi + (size_t)idx*4) = make_uint2(hu[0], hu[1]);
  *reinterpret_cast<uint2*>(lo + (size_t)idx*4) = make_uint2(lu[0], lu[1]);
}

// ---------------- MFMA NT GEMM (unchanged from R11) ----------------
#define GST 40
__global__ __launch_bounds__(256) void gemm_bf16(const ushort* __restrict__ Ah,
                                                 const ushort* __restrict__ Al,
                                                 const float*  __restrict__ Bw,
                                                 const float*  __restrict__ bias,
                                                 float* __restrict__ Cm,
                                                 int M, int Nc, int K) {
  __shared__ ushort AsH[2][128*GST], AsL[2][128*GST];
  __shared__ ushort BsH[2][64*GST],  BsL[2][64*GST];
  const int tid = threadIdx.x;
  const int n0 = blockIdx.x * 64;
  const int m0 = blockIdx.y * 128;
  const int lane = tid & 63, wv = tid >> 6;
  const int wr = wv >> 1, wc = wv & 1;
  const int lr = lane & 15, lg = lane >> 4;
  const int ar = tid >> 1, ap = (tid & 1) << 4;
  const int br = tid >> 2, bp = (tid & 3) << 3;
  const ushort* gAh = Ah + (size_t)(m0 + ar) * K + ap;
  const ushort* gAl = Al + (size_t)(m0 + ar) * K + ap;
  const float*  gB  = Bw + (size_t)(n0 + br) * K + bp;
  uint4 rah0, rah1, ral0, ral1;
  float4 rb0, rb1;
#define G_LOAD(T) { int kk = (T)*32; \
    rah0 = *reinterpret_cast<const uint4*>(gAh + kk); \
    rah1 = *reinterpret_cast<const uint4*>(gAh + kk + 8); \
    ral0 = *reinterpret_cast<const uint4*>(gAl + kk); \
    ral1 = *reinterpret_cast<const uint4*>(gAl + kk + 8); \
    rb0 = ld4(gB + kk); rb1 = ld4(gB + kk + 4); }
#define G_WRITE(BUF) { \
    *reinterpret_cast<uint4*>(&AsH[BUF][ar*GST+ap])   = rah0; \
    *reinterpret_cast<uint4*>(&AsH[BUF][ar*GST+ap+8]) = rah1; \
    *reinterpret_cast<uint4*>(&AsL[BUF][ar*GST+ap])   = ral0; \
    *reinterpret_cast<uint4*>(&AsL[BUF][ar*GST+ap+8]) = ral1; \
    float bv[8] = {rb0.x,rb0.y,rb0.z,rb0.w,rb1.x,rb1.y,rb1.z,rb1.w}; \
    uint hu[4], lu[4]; \
    _Pragma("unroll") for (int e = 0; e < 4; ++e) { \
      float x0 = bv[2*e], x1 = bv[2*e+1]; \
      uint h0 = bf16rtn(x0), h1 = bf16rtn(x1); \
      float d0 = x0 - __uint_as_float(h0 << 16); \
      float d1 = x1 - __uint_as_float(h1 << 16); \
      hu[e] = h0 | (h1 << 16); \
      lu[e] = (__float_as_uint(d0) >> 16) | (__float_as_uint(d1) & 0xFFFF0000u); } \
    *reinterpret_cast<uint4*>(&BsH[BUF][br*GST+bp]) = make_uint4(hu[0],hu[1],hu[2],hu[3]); \
    *reinterpret_cast<uint4*>(&BsL[BUF][br*GST+bp]) = make_uint4(lu[0],lu[1],lu[2],lu[3]); }

  f32x4 acc[4][2];
#pragma unroll
  for (int pf = 0; pf < 4; ++pf)
#pragma unroll
    for (int ff = 0; ff < 2; ++ff) acc[pf][ff] = (f32x4)0.f;

  G_LOAD(0);
  G_WRITE(0);
  G_LOAD(1);
  const int NT = K / 32;
  int cur = 0;
  RAW_BAR();
  for (int t = 0; t < NT; ++t) {
    short8 a_h[4], a_l[4], b_h[2], b_l[2];
#pragma unroll
    for (int pf = 0; pf < 4; ++pf) {
      int row = wr*64 + pf*16 + lr;
      a_h[pf] = *reinterpret_cast<const short8*>(&AsH[cur][row*GST + lg*8]);
      a_l[pf] = *reinterpret_cast<const short8*>(&AsL[cur][row*GST + lg*8]);
    }
#pragma unroll
    for (int ff = 0; ff < 2; ++ff) {
      int col = wc*32 + ff*16 + lr;
      b_h[ff] = *reinterpret_cast<const short8*>(&BsH[cur][col*GST + lg*8]);
      b_l[ff] = *reinterpret_cast<const short8*>(&BsL[cur][col*GST + lg*8]);
    }
    if (t < NT-1) { G_WRITE(cur^1); }
    if (t < NT-2) { G_LOAD(t+2); }
#pragma unroll
    for (int pf = 0; pf < 4; ++pf)
#pragma unroll
      for (int ff = 0; ff < 2; ++ff) {
        acc[pf][ff] = __builtin_amdgcn_mfma_f32_16x16x32_bf16(a_h[pf], b_h[ff], acc[pf][ff], 0, 0, 0);
        acc[pf][ff] = __builtin_amdgcn_mfma_f32_16x16x32_bf16(a_h[pf], b_l[ff], acc[pf][ff], 0, 0, 0);
        acc[pf][ff] = __builtin_amdgcn_mfma_f32_16x16x32_bf16(a_l[pf], b_h[ff], acc[pf][ff], 0, 0, 0);
      }
    RAW_BAR();
    cur ^= 1;
  }
#pragma unroll
  for (int pf = 0; pf < 4; ++pf)
#pragma unroll
    for (int ff = 0; ff < 2; ++ff) {
      int col = n0 + wc*32 + ff*16 + lr;
      float bs = bias[col];
#pragma unroll
      for (int reg = 0; reg < 4; ++reg) {
        int row = m0 + wr*64 + pf*16 + lg*4 + reg;
        Cm[(size_t)row*Nc + col] = acc[pf][ff][reg] + bs;
      }
    }
#undef G_LOAD
#undef G_WRITE
}

// ---------------- prep: norms + layouts (unchanged) ----------------
__global__ __launch_bounds__(256) void prep2(const float* __restrict__ qkv,
                                             const float* __restrict__ temperature,
                                             float* __restrict__ Qb,
                                             float* __restrict__ KbT,
                                             ushort* __restrict__ VhT,
                                             ushort* __restrict__ VlT) {
  __shared__ float Ks[64*65];
  __shared__ float Vs[64*65];
  const int nb = blockIdx.x;
  const int h  = blockIdx.y;
  const int lane = threadIdx.x & 63;
  const int w = threadIdx.x >> 6;
  const float temp = temperature[h];
  const float CINV = 0.05103103630798288f;
  const float S4   = 2.6321480259049848f;
  for (int r = 0; r < 16; ++r) {
    const int nl = w*16 + r;
    const int n  = nb*64 + nl;
    const float* row = qkv + (size_t)n * (3*CC) + h * DD;
    float qv = (lane < DD) ? row[lane] : 0.f;
    float kv = (lane < DD) ? row[CC + lane] : 0.f;
    float vv = (lane >= 1 && lane <= DD) ? row[2*CC + lane - 1] : 0.f;
    float qs = qv * CINV;
    float q2 = qs * qs;
    float k2 = kv * kv;
#pragma unroll
    for (int off = 32; off > 0; off >>= 1) {
      q2 += __shfl_xor(q2, off);
      k2 += __shfl_xor(k2, off);
    }
    float qn = qs / fmaxf(sqrtf(q2), 1e-12f) * (S4 * temp);
    float kn = kv / fmaxf(sqrtf(k2), 1e-12f) * S4;
    float qo = (lane < DD) ? qn : ((lane == DD) ? 6.928203230275509f : 0.f);
    float ko = (lane < DD) ? kn : ((lane == DD) ? 1.f : 0.f);
    float vo = (lane == 0) ? (1.f/NN) : ((lane <= DD) ? vv * (1.f/NN) : 0.f);
    Qb[((size_t)h * NN + n) * DP + lane] = qo;
    Ks[nl*65 + lane] = ko;
    Vs[nl*65 + lane] = vo;
  }
  __syncthreads();
  const int ch = threadIdx.x >> 2;
  const int q4 = threadIdx.x & 3;
  float kc[16], vc[16];
#pragma unroll
  for (int e = 0; e < 16; ++e) {
    int nl = q4*16 + e;
    kc[e] = Ks[nl*65 + ch];
    vc[e] = Vs[nl*65 + ch];
  }
  size_t tbase = ((size_t)h*64 + ch) * NN + nb*64 + q4*16;
#pragma unroll
  for (int e = 0; e < 16; e += 4)
    st4(KbT + tbase + e, make_float4(kc[e], kc[e+1], kc[e+2], kc[e+3]));
  uint hu[8], lu[8];
#pragma unroll
  for (int e = 0; e < 8; ++e) {
    float v0 = vc[2*e], v1 = vc[2*e+1];
    uint h0 = bf16rtn(v0), h1 = bf16rtn(v1);
    float d0 = v0 - __uint_as_float(h0 << 16);
    float d1 = v1 - __uint_as_float(h1 << 16);
    uint t0 = __float_as_uint(d0), t1 = __float_as_uint(d1);
    hu[e] = h0 | (h1 << 16);
    lu[e] = (t0 >> 16) | (t1 & 0xFFFF0000u);
  }
  *reinterpret_cast<uint4*>(VhT + tbase)     = make_uint4(hu[0],hu[1],hu[2],hu[3]);
  *reinterpret_cast<uint4*>(VhT + tbase + 8) = make_uint4(hu[4],hu[5],hu[6],hu[7]);
  *reinterpret_cast<uint4*>(VlT + tbase)     = make_uint4(lu[0],lu[1],lu[2],lu[3]);
  *reinterpret_cast<uint4*>(VlT + tbase + 8) = make_uint4(lu[4],lu[5],lu[6],lu[7]);
}

// ---------------- kvmod via MFMA (unchanged from R11: old enumeration) -------
#define KST 40
#define KNST 36
__global__ __launch_bounds__(256) void kvmod_mfma(const float* __restrict__ KbT,
                                                  const ushort* __restrict__ VhT,
                                                  const ushort* __restrict__ VlT,
                                                  float* __restrict__ Mp) {
  __shared__ ushort KKh[256*KST];
  __shared__ ushort KKl[256*KST];
  __shared__ float  KnS[64*KNST];
  __shared__ ushort VhS[64*KST];
  __shared__ ushort VlS[64*KST];
  const int tid  = threadIdx.x;
  const int bid  = blockIdx.x;        // 0..319 ; h = bid&7 pins head to XCD
  const int h    = bid & 7;
  const int idx  = bid >> 3;
  const int p0   = (idx % 5) * 256;
  const int part = idx / 5;
  const int nbase = part * 512;
  int ii = 63, jj = 63;
  {
    int pg = p0 + tid;
    if (pg < NPAIR) {
      int i = 0, rem = pg;
      while (rem >= 49 - i) { rem -= 49 - i; ++i; }
      ii = i; jj = i + rem;
    }
  }
  const float* krow_i = &KnS[ii*KNST];
  const float* krow_j = &KnS[jj*KNST];
  const int sch = tid >> 2;
  const int sq  = tid & 3;
  const size_t kgbase = ((size_t)h*64 + sch) * NN + nbase;
  const int lane = tid & 63, wv = tid >> 6;
  const int lr = lane & 15, lg = lane >> 4;
  f32x4 acc[4][4];
#pragma unroll
  for (int a = 0; a < 4; ++a)
#pragma unroll
    for (int b = 0; b < 4; ++b) acc[a][b] = (f32x4)0.f;

  float4 pa0, pa1; uint4 pvh, pvl;
#define PRE_LOAD(T) { int k0_ = (T)*32; \
    pa0 = ld4(KbT + kgbase + k0_ + sq*8); \
    pa1 = ld4(KbT + kgbase + k0_ + sq*8 + 4); \
    pvh = *reinterpret_cast<const uint4*>(VhT + kgbase + k0_ + sq*8); \
    pvl = *reinterpret_cast<const uint4*>(VlT + kgbase + k0_ + sq*8); }
#define STAGE_WRITE() { \
    st4(&KnS[sch*KNST + sq*8], pa0); \
    st4(&KnS[sch*KNST + sq*8 + 4], pa1); \
    *reinterpret_cast<uint4*>(&VhS[sch*KST + sq*8]) = pvh; \
    *reinterpret_cast<uint4*>(&VlS[sch*KST + sq*8]) = pvl; }

  PRE_LOAD(0);
  for (int t = 0; t < 16; ++t) {
    RAW_BAR();
    STAGE_WRITE();
    if (t < 15) { PRE_LOAD(t+1); }
    RAW_BAR();
    {
      uint hu[16], lu[16];
#pragma unroll
      for (int g = 0; g < 8; ++g) {
        float4 a = ld4(krow_i + g*4);
        float4 b = ld4(krow_j + g*4);
        float m0 = a.x*b.x, m1 = a.y*b.y, m2 = a.z*b.z, m3 = a.w*b.w;
        uint h0 = bf16rtn(m0), h1 = bf16rtn(m1), h2 = bf16rtn(m2), h3 = bf16rtn(m3);
        float d0 = m0 - __uint_as_float(h0 << 16);
        float d1 = m1 - __uint_as_float(h1 << 16);
        float d2 = m2 - __uint_as_float(h2 << 16);
        float d3 = m3 - __uint_as_float(h3 << 16);
        uint t0 = __float_as_uint(d0), t1 = __float_as_uint(d1);
        uint t2 = __float_as_uint(d2), t3 = __float_as_uint(d3);
        hu[2*g]   = h0 | (h1 << 16);
        hu[2*g+1] = h2 | (h3 << 16);
        lu[2*g]   = (t0 >> 16) | (t1 & 0xFFFF0000u);
        lu[2*g+1] = (t2 >> 16) | (t3 & 0xFFFF0000u);
      }
      uint4* dh = reinterpret_cast<uint4*>(&KKh[tid*KST]);
      uint4* dl = reinterpret_cast<uint4*>(&KKl[tid*KST]);
      dh[0] = make_uint4(hu[0],hu[1],hu[2],hu[3]);
      dh[1] = make_uint4(hu[4],hu[5],hu[6],hu[7]);
      dh[2] = make_uint4(hu[8],hu[9],hu[10],hu[11]);
      dh[3] = make_uint4(hu[12],hu[13],hu[14],hu[15]);
      dl[0] = make_uint4(lu[0],lu[1],lu[2],lu[3]);
      dl[1] = make_uint4(lu[4],lu[5],lu[6],lu[7]);
      dl[2] = make_uint4(lu[8],lu[9],lu[10],lu[11]);
      dl[3] = make_uint4(lu[12],lu[13],lu[14],lu[15]);
    }
    RAW_BAR();
    short8 ah[4], al[4], bh[4], bl[4];
#pragma unroll
    for (int pf = 0; pf < 4; ++pf) {
      int prow = wv*64 + pf*16 + lr;
      ah[pf] = *reinterpret_cast<const short8*>(&KKh[prow*KST + lg*8]);
      al[pf] = *reinterpret_cast<const short8*>(&KKl[prow*KST + lg*8]);
    }
#pragma unroll
    for (int ff = 0; ff < 4; ++ff) {
      int frow = ff*16 + lr;
      bh[ff] = *reinterpret_cast<const short8*>(&VhS[frow*KST + lg*8]);
      bl[ff] = *reinterpret_cast<const short8*>(&VlS[frow*KST + lg*8]);
    }
#pragma unroll
    for (int pf = 0; pf < 4; ++pf)
#pragma unroll
      for (int ff = 0; ff < 4; ++ff) {
        acc[pf][ff] = __builtin_amdgcn_mfma_f32_16x16x32_bf16(ah[pf], bh[ff], acc[pf][ff], 0, 0, 0);
        acc[pf][ff] = __builtin_amdgcn_mfma_f32_16x16x32_bf16(ah[pf], bl[ff], acc[pf][ff], 0, 0, 0);
        acc[pf][ff] = __builtin_amdgcn_mfma_f32_16x16x32_bf16(al[pf], bh[ff], acc[pf][ff], 0, 0, 0);
      }
  }
  float* out = Mp + ((size_t)(part*HN + h) * PPAD + p0 + wv*64) * MPF;
#pragma unroll
  for (int pf = 0; pf < 4; ++pf)
#pragma unroll
    for (int ff = 0; ff < 4; ++ff) {
      int f = ff*16 + lr;
      if (f < MPF) {
#pragma unroll
        for (int reg = 0; reg < 4; ++reg) {
          int prow = pf*16 + lg*4 + reg;
          out[prow*MPF + f] = acc[pf][ff][reg];
        }
      }
    }
#undef PRE_LOAD
#undef STAGE_WRITE
}

// ---------------- reduce parts -> f-major pair-transposed bf16 planes --------
// MpTh/MpTl[h][f=64][p=NP2], new aligned-chunk enumeration; dead p stay zero
// (memset). Diagonal pairs pre-scaled 0.5 (folds the global 0.5 for the GEMM);
// Mnorm[h][f] = raw sum of pair (48,48).
__global__ __launch_bounds__(256) void reduce_pair(const float* __restrict__ Mp,
                                                   ushort* __restrict__ MpTh,
                                                   ushort* __restrict__ MpTl,
                                                   float* __restrict__ Mnorm) {
  const int pb = blockIdx.x;          // 0..27
  const int h  = blockIdx.y;
  const int pl = threadIdx.x & 63;
  const int fq0 = threadIdx.x >> 6;
  const int p = pb*64 + pl;
  const int c = p >> 3, e = p & 7;
  int ci, cjb;
  chunk_ij(c, ci, cjb);
  const int j = cjb*8 + e;
  if (ci > 48 || j < ci || j > 48) return;     // dead pair: memset zero stands
  const int oldp = ci*49 - (ci*(ci-1))/2 + (j - ci);
  const float scale = (ci == j) ? 0.5f : 1.0f;
  const bool isnorm = (ci == 48) && (j == 48);
  for (int fq = fq0; fq < 13; fq += 4) {
    float4 s = make_float4(0.f, 0.f, 0.f, 0.f);
#pragma unroll
    for (int part = 0; part < 8; ++part) {
      float4 a = ld4(Mp + ((size_t)(part*HN + h) * PPAD + oldp) * MPF + fq*4);
      s.x += a.x; s.y += a.y; s.z += a.z; s.w += a.w;
    }
    if (isnorm) st4(&Mnorm[h*64 + fq*4], s);   // raw (pre-scale)
    float sv[4] = {s.x*scale, s.y*scale, s.z*scale, s.w*scale};
#pragma unroll
    for (int c4 = 0; c4 < 4; ++c4) {
      int f = fq*4 + c4;
      float v = sv[c4];
      uint hb = bf16rtn(v);
      float d = v - __uint_as_float(hb << 16);
      size_t a = ((size_t)h*64 + f) * NP2 + p;
      MpTh[a] = (ushort)hb;
      MpTl[a] = (ushort)(__float_as_uint(d) >> 16);
    }
  }
}

// ---------------- y as pair-major GEMM: y[n][f] = sum_p W[n][p] * M_p[f] -----
// W[n][p(i,j)] = q[n][i]*q[n][j] (diag 0.5 folded into M). A-frags (W) built
// per-lane in registers from row-major Qrow (aligned ld4: j-blocks 8-aligned).
// K = 1792 pairs = 56 steps, split 28/28 across zk into Yp partials.
__global__ __launch_bounds__(256, 3) void y_pair(const float* __restrict__ Qb,
                                                 const ushort* __restrict__ MpTh,
                                                 const ushort* __restrict__ MpTl,
                                                 float* __restrict__ Yp) {
  __shared__ float Qrow[128*QRS];     // [row][channel], 16B-aligned rows
  __shared__ ushort Bt[2][64*40];     // [plane][f*40 + p_local], kvmod-proven banks
  const int tid = threadIdx.x;
  const int bid = blockIdx.x;         // 0..511
  const int h   = bid & 7;            // XCD pin
  const int nt  = (bid >> 3) & 31;
  const int zk  = bid >> 8;           // K-half
  const int n0  = nt * 128;
  const int lane = tid & 63, wv = tid >> 6;
  const int wr = wv >> 1, wc = wv & 1;
  const int lr = lane & 15, lg = lane >> 4;

  // stage Qrow (128 rows x 64 ch)
  for (int v = tid; v < 128*16; v += 256) {
    int r = v >> 4, cg = v & 15;
    float4 q = ld4(Qb + ((size_t)h*NN + n0 + r)*DP + cg*4);
    float* d = &Qrow[r*QRS + cg*4];
    d[0]=q.x; d[1]=q.y; d[2]=q.z; d[3]=q.w;
  }
  // B staging: thread -> (plane, f, 16-pair half); 32 B per thread per step
  const int sp = tid >> 7;
  const int sidx = tid & 127;
  const int sf = sidx >> 1;
  const int sph = (sidx & 1) * 16;
  const ushort* gB = (sp ? MpTl : MpTh) + ((size_t)h*64 + sf)*NP2 + zk*896 + sph;
  uint4 pb0, pb1;
#define B_LOAD(T) { const uint4* gp = reinterpret_cast<const uint4*>(gB + (size_t)(T)*32); \
    pb0 = gp[0]; pb1 = gp[1]; }
#define B_WRITE() { \
    *reinterpret_cast<uint4*>(&Bt[sp][sf*40 + sph])     = pb0; \
    *reinterpret_cast<uint4*>(&Bt[sp][sf*40 + sph + 8]) = pb1; }

  f32x4 acc[4][2];
#pragma unroll
  for (int m = 0; m < 4; ++m)
#pragma unroll
    for (int ff = 0; ff < 2; ++ff) acc[m][ff] = (f32x4)0.f;

  B_LOAD(0);
  RAW_BAR();                         // Qrow staged
  for (int t = 0; t < 28; ++t) {
    B_WRITE();
    if (t < 27) { B_LOAD(t+1); }     // in flight across compute (T14)
    // chunk for this step/lane-group
    int c = (zk*28 + t)*4 + lg;
    int ci, cjb;
    chunk_ij(c, ci, cjb);
    RAW_BAR();                       // Bt visible
    short8 bfh[2], bfl[2];
#pragma unroll
    for (int ff = 0; ff < 2; ++ff) {
      int f = wc*32 + ff*16 + lr;
      bfh[ff] = *reinterpret_cast<const short8*>(&Bt[0][f*40 + lg*8]);
      bfl[ff] = *reinterpret_cast<const short8*>(&Bt[1][f*40 + lg*8]);
    }
#pragma unroll
    for (int m = 0; m < 4; ++m) {
      int row = wr*64 + m*16 + lr;
      float qi = Qrow[row*QRS + ci];
      float4 qa = ld4(&Qrow[row*QRS + cjb*8]);
      float4 qb = ld4(&Qrow[row*QRS + cjb*8 + 4]);
      float xs[8] = {qi*qa.x, qi*qa.y, qi*qa.z, qi*qa.w,
                     qi*qb.x, qi*qb.y, qi*qb.z, qi*qb.w};
      union { uint u[4]; short8 s; } uh, ul;
#pragma unroll
      for (int e2 = 0; e2 < 4; ++e2) {
        float x0 = xs[2*e2], x1 = xs[2*e2+1];
        uint h0 = bf16rtn(x0), h1 = bf16rtn(x1);
        float d0 = x0 - __uint_as_float(h0 << 16);
        float d1 = x1 - __uint_as_float(h1 << 16);
        uh.u[e2] = h0 | (h1 << 16);
        ul.u[e2] = (__float_as_uint(d0) >> 16) | (__float_as_uint(d1) & 0xFFFF0000u);
      }
#pragma unroll
      for (int ff = 0; ff < 2; ++ff) {
        acc[m][ff] = __builtin_amdgcn_mfma_f32_16x16x32_bf16(uh.s, bfh[ff], acc[m][ff], 0, 0, 0);
        acc[m][ff] = __builtin_amdgcn_mfma_f32_16x16x32_bf16(uh.s, bfl[ff], acc[m][ff], 0, 0, 0);
        acc[m][ff] = __builtin_amdgcn_mfma_f32_16x16x32_bf16(ul.s, bfh[ff], acc[m][ff], 0, 0, 0);
      }
    }
    RAW_BAR();                       // frags consumed before next B_WRITE
  }
  // write raw partials; y_combine sums zk halves, adds 24*Mnorm, divides
  float* out = Yp + ((size_t)(zk*HN + h) * NN) * 64;
#pragma unroll
  for (int m = 0; m < 4; ++m)
#pragma unroll
    for (int ff = 0; ff < 2; ++ff) {
      int f = wc*32 + ff*16 + lr;
#pragma unroll
      for (int reg = 0; reg < 4; ++reg) {
        int row = n0 + wr*64 + m*16 + lg*4 + reg;
        out[(size_t)row*64 + f] = acc[m][ff][reg];
      }
    }
#undef B_LOAD
#undef B_WRITE
}

// ---------------- combine partials -> split-bf16 attn planes -----------------
__global__ __launch_bounds__(256) void y_combine(const float* __restrict__ Yp,
                                                 const float* __restrict__ Mnorm,
                                                 ushort* __restrict__ AttnH,
                                                 ushort* __restrict__ AttnL) {
  const int h = blockIdx.y;
  const int t = threadIdx.x;
  const int r = blockIdx.x*64 + (t >> 2);
  const int fq = t & 3;
  const int lane = t & 63;
  const float* p0 = Yp + ((size_t)h*NN + r)*64 + fq*16;
  const float* p1 = Yp + ((size_t)(HN+h)*NN + r)*64 + fq*16;
  float y[16];
#pragma unroll
  for (int g = 0; g < 4; ++g) {
    float4 a = ld4(p0 + g*4);
    float4 b = ld4(p1 + g*4);
    float4 m = ld4(Mnorm + h*64 + fq*16 + g*4);
    y[g*4+0] = (a.x+b.x) + 24.f*m.x;
    y[g*4+1] = (a.y+b.y) + 24.f*m.y;
    y[g*4+2] = (a.z+b.z) + 24.f*m.z;
    y[g*4+3] = (a.w+b.w) + 24.f*m.w;
  }
  float y0 = __shfl(y[0], lane & ~3);
  float inv = 1.f / y0;
#pragma unroll
  for (int e = 0; e < 16; ++e) {
    int f = fq*16 + e;
    if (f >= 1 && f <= DD) {
      float o = y[e] * inv;
      uint hb = bf16rtn(o);
      float d = o - __uint_as_float(hb << 16);
      size_t a = (size_t)r*CC + h*DD + (f-1);
      AttnH[a] = (ushort)hb;
      AttnL[a] = (ushort)(__float_as_uint(d) >> 16);
    }
  }
}

extern "C" void kernel_launch(void* const* d_in, const int* in_sizes, int n_in,
                              void* d_out, int out_size, void* d_ws, size_t ws_size,
                              hipStream_t stream) {
  const float* x      = (const float*)d_in[0];
  const float* qkv_w  = (const float*)d_in[1];
  const float* qkv_b  = (const float*)d_in[2];
  const float* proj_w = (const float*)d_in[3];
  const float* proj_b = (const float*)d_in[4];
  const float* temp   = (const float*)d_in[5];
  float* ws = (float*)d_ws;

  // Region A [0, 4,718,592): qkv -> Mp (8*8*1280*52 = 4,259,840) -> Yp (4,194,304)
  float*  qkv  = ws;
  float*  Mp   = ws;
  float*  Yp   = ws;
  // Region B: Qb
  float*  Qb   = ws + 4718592;
  // Region C [6,815,744, 8,912,896): Xh|Xl -> KbT -> (MpTh | MpTl | Mnorm)
  ushort* Xh   = (ushort*)(ws + 6815744);
  ushort* Xl   = Xh + 1572864;
  float*  KbT  = ws + 6815744;
  ushort* MpTh = (ushort*)(ws + 6815744);          // 8*64*1792 = 917,504 us
  ushort* MpTl = MpTh + 917504;
  float*  Mnorm= ws + 6815744 + 917504;            // 512 f (after both planes)
  // Region D [8,912,896, ...): VhT|VlT -> AttnH|AttnL
  ushort* VhT  = (ushort*)(ws + 8912896);
  ushort* VlT  = (ushort*)(ws + 9961472);
  ushort* AttnH= (ushort*)(ws + 8912896);
  ushort* AttnL= AttnH + 1572864;

  split_f32<<<1536, 256, 0, stream>>>(x, Xh, Xl, NN*CC/4);
  {
    dim3 g(1152/64, 4096/128);
    gemm_bf16<<<g, 256, 0, stream>>>(Xh, Xl, qkv_w, qkv_b, qkv, 4096, 1152, 384);
  }
  {
    dim3 g(64, HN);
    prep2<<<g, 256, 0, stream>>>(qkv, temp, Qb, KbT, VhT, VlT);
  }
  kvmod_mfma<<<320, 256, 0, stream>>>(KbT, VhT, VlT, Mp);
  // zero MpT planes + Mnorm (dead pairs / f>=52 must be 0); KbT dead now
  hipMemsetAsync((void*)MpTh, 0, (size_t)917504*2*2 + 2048, stream);
  {
    dim3 g(NP2/64, HN);
    reduce_pair<<<g, 256, 0, stream>>>(Mp, MpTh, MpTl, Mnorm);
  }
  y_pair<<<512, 256, 0, stream>>>(Qb, MpTh, MpTl, Yp);
  {
    dim3 g(4096/64, HN);
    y_combine<<<g, 256, 0, stream>>>(Yp, Mnorm, AttnH, AttnL);
  }
  {
    dim3 g(384/64, 4096/128);
    gemm_bf16<<<g, 256, 0, stream>>>(AttnH, AttnL, proj_w, proj_b, (float*)d_out, 4096, 384, 384);
  }
}